// Round 2
// baseline (6335.153 us; speedup 1.0000x reference)
//
#include <hip/hip_runtime.h>
#include <hip/hip_bf16.h>
#include <math.h>

// Shapes
#define B_  16
#define S_  64
#define R_  6
#define L_  24
#define D_  128
#define H_  256
// derived
#define BS_   1024    // B*S
#define BSR_  6144    // B*S*R

__device__ __forceinline__ float sigmoidf_(float x) { return 1.f / (1.f + __expf(-x)); }

// ---------------------------------------------------------------------------
// Generic tiled fp32 GEMM: C[m,n] = bias[n] + sum_k A(m,k) * B[n*ldb + k]
//   A(m,k) = (k < K1) ? A1[m*lda1 + k] : A2[m*lda2 + (k-K1)]   (concat support)
// MODE 0: plain store to C (ldc)
// MODE 1: fused GRU gate epilogue. N must be 1024 with weight rows ordered as
//         row 4*j+c : c=0 r-gate, c=1 z-gate, c=2 xn (x-part only), c=3 hn
//         (h-part only). Writes h_out = C (6144x256) and his_last when
//         t == len[m]-1.
// ---------------------------------------------------------------------------
#define BM 64
#define BN 64
#define BK 16

template<int MODE>
__global__ __launch_bounds__(256) void gemm_k(
    const float* __restrict__ A1, int lda1, int K1,
    const float* __restrict__ A2, int lda2,
    const float* __restrict__ Bm, int ldb,
    const float* __restrict__ bias,
    float* __restrict__ C, int ldc,
    int M, int N, int K,
    const float* __restrict__ h_in,
    float* __restrict__ his_last,
    const int* __restrict__ len, int t)
{
    __shared__ float As[BK][BM + 4];
    __shared__ float Bs[BK][BN + 4];
    const int tid = threadIdx.x;
    const int m0 = blockIdx.x * BM;
    const int n0 = blockIdx.y * BN;
    const int tx = tid & 15, ty = tid >> 4;
    const int lr  = tid >> 2;          // 0..63
    const int lk0 = (tid & 3) << 2;    // 0,4,8,12
    float acc[4][4] = {};

    for (int k0 = 0; k0 < K; k0 += BK) {
        #pragma unroll
        for (int i = 0; i < 4; ++i) {
            int k = k0 + lk0 + i;
            int m = m0 + lr;
            float va = 0.f;
            if (m < M && k < K)
                va = (k < K1) ? A1[(size_t)m * lda1 + k]
                              : A2[(size_t)m * lda2 + (k - K1)];
            As[lk0 + i][lr] = va;
            int nn = n0 + lr;
            float vb = 0.f;
            if (nn < N && k < K) vb = Bm[(size_t)nn * ldb + k];
            Bs[lk0 + i][lr] = vb;
        }
        __syncthreads();
        #pragma unroll
        for (int kk = 0; kk < BK; ++kk) {
            const float4 a4 = *(const float4*)&As[kk][ty << 2];
            const float4 b4 = *(const float4*)&Bs[kk][tx << 2];
            const float a[4] = {a4.x, a4.y, a4.z, a4.w};
            const float b[4] = {b4.x, b4.y, b4.z, b4.w};
            #pragma unroll
            for (int i = 0; i < 4; ++i)
                #pragma unroll
                for (int j = 0; j < 4; ++j)
                    acc[i][j] = fmaf(a[i], b[j], acc[i][j]);
        }
        __syncthreads();
    }

    if (MODE == 0) {
        #pragma unroll
        for (int i = 0; i < 4; ++i) {
            int m = m0 + (ty << 2) + i;
            if (m >= M) continue;
            #pragma unroll
            for (int j = 0; j < 4; ++j) {
                int nn = n0 + (tx << 2) + j;
                if (nn < N) C[(size_t)m * ldc + nn] = acc[i][j] + (bias ? bias[nn] : 0.f);
            }
        }
    } else {
        const int jj = (n0 >> 2) + tx;  // hidden unit 0..255
        #pragma unroll
        for (int i = 0; i < 4; ++i) {
            int m = m0 + (ty << 2) + i;
            if (m >= M) continue;
            float rp = acc[i][0] + bias[(jj << 2) + 0];
            float zp = acc[i][1] + bias[(jj << 2) + 1];
            float xn = acc[i][2] + bias[(jj << 2) + 2];
            float hn = acc[i][3] + bias[(jj << 2) + 3];
            float r = sigmoidf_(rp);
            float z = sigmoidf_(zp);
            float ng = tanhf(xn + r * hn);
            float hprev = h_in[(size_t)m * H_ + jj];
            float hnew = (1.f - z) * ng + z * hprev;
            C[(size_t)m * H_ + jj] = hnew;
            if (t == len[m] - 1) his_last[(size_t)m * H_ + jj] = hnew;
        }
    }
}

// ---------------------------------------------------------------------------
// Build interleaved gate weight matrix Wbig (1024 x 384) + bias_big (1024)
// row 4*j+0: [w_ih_r[j] | w_hh_r[j]]        bias b_ih[j]+b_hh[j]
// row 4*j+1: [w_ih_z[j] | w_hh_z[j]]        bias b_ih[256+j]+b_hh[256+j]
// row 4*j+2: [w_ih_n[j] | 0        ]        bias b_ih[512+j]
// row 4*j+3: [0         | w_hh_n[j]]        bias b_hh[512+j]
// ---------------------------------------------------------------------------
__global__ void prep_wbig(const float* __restrict__ w_ih, const float* __restrict__ w_hh,
                          const float* __restrict__ b_ih, const float* __restrict__ b_hh,
                          float* __restrict__ Wbig, float* __restrict__ bias_big)
{
    int idx = blockIdx.x * 256 + threadIdx.x;
    if (idx >= 1024 * 384) return;
    int row = idx / 384, k = idx % 384;
    int j = row >> 2, c = row & 3;
    float v = 0.f;
    if (c == 0)      v = (k < 128) ? w_ih[j * 128 + k]          : w_hh[j * 256 + (k - 128)];
    else if (c == 1) v = (k < 128) ? w_ih[(256 + j) * 128 + k]  : w_hh[(256 + j) * 256 + (k - 128)];
    else if (c == 2) v = (k < 128) ? w_ih[(512 + j) * 128 + k]  : 0.f;
    else             v = (k < 128) ? 0.f                         : w_hh[(512 + j) * 256 + (k - 128)];
    Wbig[idx] = v;
    if (k == 0) {
        float bb;
        if (c == 0)      bb = b_ih[j] + b_hh[j];
        else if (c == 1) bb = b_ih[256 + j] + b_hh[256 + j];
        else if (c == 2) bb = b_ih[512 + j];
        else             bb = b_hh[512 + j];
        bias_big[row] = bb;
    }
}

// ---------------------------------------------------------------------------
// Intra GRU: one block per batch element (16 blocks x 256 threads), 64 steps.
// Thread jj computes gates r,z,xn,hn via Wbig rows 4jj..4jj+3 (zero parts
// skipped). Writes all hidden states to intra_h (16,64,256).
// ---------------------------------------------------------------------------
__global__ __launch_bounds__(256) void intra_gru(
    const float* __restrict__ x, const float* __restrict__ Wbig,
    const float* __restrict__ biasb, float* __restrict__ ih)
{
    __shared__ float xs[D_];
    __shared__ float hs[H_];
    const int b = blockIdx.x, tid = threadIdx.x;
    hs[tid] = 0.f;
    const float* xb = x + (size_t)b * S_ * D_;
    const float* w0 = Wbig + (size_t)(4 * tid + 0) * 384;
    const float* w1 = Wbig + (size_t)(4 * tid + 1) * 384;
    const float* w2 = Wbig + (size_t)(4 * tid + 2) * 384;
    const float* w3 = Wbig + (size_t)(4 * tid + 3) * 384;
    const float bb0 = biasb[4 * tid + 0];
    const float bb1 = biasb[4 * tid + 1];
    const float bb2 = biasb[4 * tid + 2];
    const float bb3 = biasb[4 * tid + 3];
    __syncthreads();
    for (int t = 0; t < S_; ++t) {
        if (tid < D_) xs[tid] = xb[t * D_ + tid];
        __syncthreads();
        float s0 = bb0, s1 = bb1, s2 = bb2, s3 = bb3;
        for (int k = 0; k < D_; ++k) {
            float xv = xs[k];
            s0 = fmaf(xv, w0[k], s0);
            s1 = fmaf(xv, w1[k], s1);
            s2 = fmaf(xv, w2[k], s2);
        }
        for (int k = 0; k < H_; ++k) {
            float hv = hs[k];
            s0 = fmaf(hv, w0[128 + k], s0);
            s1 = fmaf(hv, w1[128 + k], s1);
            s3 = fmaf(hv, w3[128 + k], s3);
        }
        float r = sigmoidf_(s0);
        float z = sigmoidf_(s1);
        float ng = tanhf(s2 + r * s3);
        float hnew = (1.f - z) * ng + z * hs[tid];
        __syncthreads();
        hs[tid] = hnew;
        ih[((size_t)b * S_ + t) * H_ + tid] = hnew;
        __syncthreads();
    }
}

// ---------------------------------------------------------------------------
// Concat / pack kernels
// ---------------------------------------------------------------------------
__global__ void concat_mrv(const float* __restrict__ hl, const float* __restrict__ ir,
                           float* __restrict__ Mrv)
{
    int idx = blockIdx.x * 256 + threadIdx.x;          // BSR_*384
    if (idx >= BSR_ * 384) return;
    int c = idx % 384, pr = idx / 384;
    Mrv[idx] = (c < 256) ? hl[(size_t)pr * 256 + c] : ir[(size_t)pr * 128 + (c - 256)];
}

__global__ void concat_mpv(const float* __restrict__ ihf, const float* __restrict__ x,
                           float* __restrict__ mpv)
{
    int idx = blockIdx.x * 256 + threadIdx.x;          // BS_*384
    if (idx >= BS_ * 384) return;
    int c = idx % 384, p = idx / 384;
    float v = 0.f;
    if (c < 256)      v = ihf[(size_t)p * 256 + c];
    else if (c < 383) v = x[(size_t)p * 128 + (c - 256)];
    mpv[idx] = v;
}

__global__ void concat_ihp(const float* __restrict__ ihf, const float* __restrict__ x,
                           float* __restrict__ ihp)
{
    int idx = blockIdx.x * 256 + threadIdx.x;          // BS_*260
    if (idx >= BS_ * 260) return;
    int c = idx % 260, p = idx / 260;
    float v = 0.f;
    if (c < 256)       v = ihf[(size_t)p * 256 + c];
    else if (c == 256) v = x[(size_t)p * 128 + 127];
    ihp[idx] = v;
}

__global__ void combine_feat(const float* __restrict__ vv, const float* __restrict__ vh,
                             const float* __restrict__ ihf, const float* __restrict__ x,
                             const float* __restrict__ wr, float* __restrict__ feat)
{
    int idx = blockIdx.x * 256 + threadIdx.x;          // BS_*640
    if (idx >= BS_ * 640) return;
    int c = idx % 640, p = idx / 640;
    float e0 = __expf(wr[0]), e1 = __expf(wr[1]);
    float w0 = e0 / (e0 + e1), w1 = e1 / (e0 + e1);
    float v = 0.f;
    if (c < 256)      v = w0 * vv[(size_t)p * 256 + c] + w1 * vh[(size_t)p * 256 + c];
    else if (c < 512) v = ihf[(size_t)p * 256 + (c - 256)];
    else if (c < 639) v = x[(size_t)p * 128 + (c - 512)];
    feat[idx] = v;
}

// ---------------------------------------------------------------------------
// v_v attention: R=6 keys, 1 query per (p, head). One wave per (p, head).
// ---------------------------------------------------------------------------
__global__ __launch_bounds__(256) void attn_vv(
    const float* __restrict__ q,   // (1024,256)
    const float* __restrict__ k,   // (6144,256)
    const float* __restrict__ v,   // (6144,256)
    float* __restrict__ o)         // (1024,256)
{
    int wid = (blockIdx.x * 256 + threadIdx.x) >> 6;   // 0..2047
    int lane = threadIdx.x & 63;
    int p = wid >> 1, head = wid & 1;
    int d0 = head * 128 + lane * 2;
    const float* qp = q + (size_t)p * 256 + d0;
    float q0 = qp[0], q1 = qp[1];
    float sc[R_];
    #pragma unroll
    for (int r = 0; r < R_; ++r) {
        const float* kp = k + (size_t)(p * R_ + r) * 256 + d0;
        float s = q0 * kp[0] + q1 * kp[1];
        #pragma unroll
        for (int off = 32; off; off >>= 1) s += __shfl_xor(s, off, 64);
        sc[r] = s * 0.08838834764831845f;   // 1/sqrt(128)
    }
    float mx = sc[0];
    #pragma unroll
    for (int r = 1; r < R_; ++r) mx = fmaxf(mx, sc[r]);
    float sum = 0.f;
    #pragma unroll
    for (int r = 0; r < R_; ++r) { sc[r] = __expf(sc[r] - mx); sum += sc[r]; }
    float inv = 1.f / sum;
    float o0 = 0.f, o1 = 0.f;
    #pragma unroll
    for (int r = 0; r < R_; ++r) {
        const float* vp = v + (size_t)(p * R_ + r) * 256 + d0;
        o0 += sc[r] * vp[0];
        o1 += sc[r] * vp[1];
    }
    o[(size_t)p * 256 + d0]     = o0 * inv;
    o[(size_t)p * 256 + d0 + 1] = o1 * inv;
}

// ---------------------------------------------------------------------------
// v_h attention: causal 64x64 per (b, head). One wave per (b, head, q-row).
// ---------------------------------------------------------------------------
__global__ __launch_bounds__(256) void attn_vh(
    const float* __restrict__ q,   // (1024,256)
    const float* __restrict__ k,   // (1024,256)
    const float* __restrict__ v,   // (1024,256)
    float* __restrict__ o)         // (1024,256)
{
    __shared__ float ps[4][64];
    int widb = threadIdx.x >> 6;
    int wid = blockIdx.x * 4 + widb;                   // 0..2047
    int lane = threadIdx.x & 63;
    int b = wid >> 7;
    int rem = wid & 127;
    int head = rem >> 6;
    int qi = rem & 63;
    const float* qrow = q + ((size_t)b * 64 + qi) * 256 + head * 128;
    const float* krow = k + ((size_t)b * 64 + lane) * 256 + head * 128;
    float sA = 0.f, sB = 0.f;
    for (int d = 0; d < 128; d += 2) {
        sA = fmaf(qrow[d],     krow[d],     sA);
        sB = fmaf(qrow[d + 1], krow[d + 1], sB);
    }
    float s = (sA + sB) * 0.08838834764831845f;
    bool valid = (lane <= qi);
    float smax = valid ? s : -1e30f;
    #pragma unroll
    for (int off = 32; off; off >>= 1) smax = fmaxf(smax, __shfl_xor(smax, off, 64));
    float e = valid ? __expf(s - smax) : 0.f;
    float ssum = e;
    #pragma unroll
    for (int off = 32; off; off >>= 1) ssum += __shfl_xor(ssum, off, 64);
    float pv = e / ssum;
    ps[widb][lane] = pv;
    __syncthreads();
    float o0 = 0.f, o1 = 0.f;
    for (int j = 0; j <= qi; ++j) {
        float pj = ps[widb][j];
        const float* vrow = v + ((size_t)b * 64 + j) * 256 + head * 128;
        o0 = fmaf(pj, vrow[lane],      o0);
        o1 = fmaf(pj, vrow[lane + 64], o1);
    }
    o[((size_t)b * 64 + qi) * 256 + head * 128 + lane]      = o0;
    o[((size_t)b * 64 + qi) * 256 + head * 128 + lane + 64] = o1;
}

// ---------------------------------------------------------------------------
extern "C" void kernel_launch(void* const* d_in, const int* in_sizes, int n_in,
                              void* d_out, int out_size, void* d_ws, size_t ws_size,
                              hipStream_t stream)
{
    const float* intra_x   = (const float*)d_in[0];
    const float* inter_his = (const float*)d_in[1];
    const float* inter_r   = (const float*)d_in[2];
    const int*   inter_len = (const int*)  d_in[4];
    const float* w_ih = (const float*)d_in[5];
    const float* w_hh = (const float*)d_in[6];
    const float* b_ih = (const float*)d_in[7];
    const float* b_hh = (const float*)d_in[8];
    const float* iq_w = (const float*)d_in[9];
    const float* iq_b = (const float*)d_in[10];
    const float* ik_w = (const float*)d_in[11];
    const float* ik_b = (const float*)d_in[12];
    const float* iv_w = (const float*)d_in[13];
    const float* iv_b = (const float*)d_in[14];
    const float* io_w = (const float*)d_in[15];
    const float* io_b = (const float*)d_in[16];
    const float* aq_w = (const float*)d_in[17];
    const float* aq_b = (const float*)d_in[18];
    const float* ak_w = (const float*)d_in[19];
    const float* ak_b = (const float*)d_in[20];
    const float* av_w = (const float*)d_in[21];
    const float* av_b = (const float*)d_in[22];
    const float* ao_w = (const float*)d_in[23];
    const float* ao_b = (const float*)d_in[24];
    const float* wr   = (const float*)d_in[25];
    const float* ln_w = (const float*)d_in[26];
    const float* ln_b = (const float*)d_in[27];
    float* out = (float*)d_out;

    char* ws = (char*)d_ws;
    size_t off = 0;
    auto alloc = [&](size_t bytes) -> float* {
        char* p = ws + off;
        off += (bytes + 255) & ~(size_t)255;
        return (float*)p;
    };
    float* Wbig    = alloc(1024 * 384 * 4);
    float* biasb   = alloc(1024 * 4);
    float* h_ping  = alloc((size_t)BSR_ * H_ * 4);
    float* h_pong  = alloc((size_t)BSR_ * H_ * 4);
    float* hislast = alloc((size_t)BSR_ * H_ * 4);
    float* intraH  = alloc((size_t)BS_ * H_ * 4);
    float* Mrv     = alloc((size_t)BSR_ * 384 * 4);
    float* mpv     = alloc((size_t)BS_ * 384 * 4);
    float* qbuf    = alloc((size_t)BS_ * 256 * 4);
    float* kbuf    = alloc((size_t)BSR_ * 256 * 4);
    float* vbuf    = alloc((size_t)BSR_ * 256 * 4);
    float* attno   = alloc((size_t)BS_ * 256 * 4);
    float* vv      = alloc((size_t)BS_ * 256 * 4);
    float* ihp     = alloc((size_t)BS_ * 260 * 4);
    float* qa      = alloc((size_t)BS_ * 256 * 4);
    float* ka      = alloc((size_t)BS_ * 256 * 4);
    float* va      = alloc((size_t)BS_ * 256 * 4);
    float* aho     = alloc((size_t)BS_ * 256 * 4);
    float* vhb     = alloc((size_t)BS_ * 256 * 4);
    float* feat    = alloc((size_t)BS_ * 640 * 4);
    (void)ws_size; (void)in_sizes; (void)n_in; (void)out_size;

    auto gemm = [&](const float* A, int lda, const float* Bw, int ldb,
                    const float* bias, float* C, int M, int N, int K) {
        gemm_k<0><<<dim3((M + BM - 1) / BM, (N + BN - 1) / BN), 256, 0, stream>>>(
            A, lda, K, A, 0, Bw, ldb, bias, C, N, M, N, K,
            nullptr, nullptr, nullptr, 0);
    };

    // weight prep + intra GRU
    prep_wbig<<<1536, 256, 0, stream>>>(w_ih, w_hh, b_ih, b_hh, Wbig, biasb);
    hipMemsetAsync(h_ping, 0, (size_t)BSR_ * H_ * 4, stream);
    intra_gru<<<B_, 256, 0, stream>>>(intra_x, Wbig, biasb, intraH);

    // inter GRU: 24 fused GEMM+gate steps
    for (int t = 0; t < L_; ++t) {
        const float* hin = (t & 1) ? h_pong : h_ping;
        float* hout      = (t & 1) ? h_ping : h_pong;
        gemm_k<1><<<dim3(BSR_ / BM, 1024 / BN), 256, 0, stream>>>(
            inter_his + (size_t)t * D_, L_ * D_, D_, hin, H_,
            Wbig, 384, biasb, hout, H_, BSR_, 1024, 384,
            hin, hislast, inter_len, t);
    }

    // v_v branch
    concat_mrv<<<(BSR_ * 384 + 255) / 256, 256, 0, stream>>>(hislast, inter_r, Mrv);
    concat_mpv<<<(BS_ * 384 + 255) / 256, 256, 0, stream>>>(intraH, intra_x, mpv);
    gemm(mpv, 384, iq_w, 383, iq_b, qbuf, BS_, 256, 383);
    gemm(Mrv, 384, ik_w, 383, ik_b, kbuf, BSR_, 256, 383);
    gemm(Mrv, 384, iv_w, 384, iv_b, vbuf, BSR_, 256, 384);
    attn_vv<<<512, 256, 0, stream>>>(qbuf, kbuf, vbuf, attno);
    gemm(attno, 256, io_w, 256, io_b, vv, BS_, 256, 256);

    // v_h branch
    concat_ihp<<<(BS_ * 260 + 255) / 256, 256, 0, stream>>>(intraH, intra_x, ihp);
    gemm(intra_x, 128, aq_w, 127, aq_b, qa, BS_, 256, 127);
    gemm(intra_x, 128, ak_w, 127, ak_b, ka, BS_, 256, 127);
    gemm(ihp, 260, av_w, 257, av_b, va, BS_, 256, 257);
    attn_vh<<<512, 256, 0, stream>>>(qa, ka, va, aho);
    gemm(aho, 256, ao_w, 256, ao_b, vhb, BS_, 256, 256);

    // combine + final projection
    combine_feat<<<(BS_ * 640 + 255) / 256, 256, 0, stream>>>(vv, vhb, intraH, intra_x, wr, feat);
    gemm(feat, 640, ln_w, 639, ln_b, out, BS_, 256, 639);
}

// Round 3
// 5090.251 us; speedup vs baseline: 1.2446x; 1.2446x over previous
//
#include <hip/hip_runtime.h>
#include <hip/hip_bf16.h>
#include <math.h>

// Shapes
#define B_  16
#define S_  64
#define R_  6
#define L_  24
#define D_  128
#define H_  256
// derived
#define BS_   1024    // B*S
#define BSR_  6144    // B*S*R

__device__ __forceinline__ float sigmoidf_(float x) { return 1.f / (1.f + __expf(-x)); }

// ---------------------------------------------------------------------------
// Generic tiled fp32 GEMM: C[m,n] = bias[n] + sum_k A(m,k) * B[n*ldb + k]
//   A(m,k) = (k < K1) ? A1[m*lda1 + k] : A2[m*lda2 + (k-K1)]   (concat support)
// MODE 0: plain store to C (ldc)
// MODE 1: fused GRU gate epilogue (see prep_wbig row order).
// ---------------------------------------------------------------------------
#define BM 64
#define BN 64
#define BK 16

template<int MODE>
__global__ __launch_bounds__(256) void gemm_k(
    const float* __restrict__ A1, int lda1, int K1,
    const float* __restrict__ A2, int lda2,
    const float* __restrict__ Bm, int ldb,
    const float* __restrict__ bias,
    float* __restrict__ C, int ldc,
    int M, int N, int K,
    const float* __restrict__ h_in,
    float* __restrict__ his_last,
    const int* __restrict__ len, int t)
{
    __shared__ float As[BK][BM + 4];
    __shared__ float Bs[BK][BN + 4];
    const int tid = threadIdx.x;
    const int m0 = blockIdx.x * BM;
    const int n0 = blockIdx.y * BN;
    const int tx = tid & 15, ty = tid >> 4;
    const int lr  = tid >> 2;          // 0..63
    const int lk0 = (tid & 3) << 2;    // 0,4,8,12
    float acc[4][4] = {};

    for (int k0 = 0; k0 < K; k0 += BK) {
        #pragma unroll
        for (int i = 0; i < 4; ++i) {
            int k = k0 + lk0 + i;
            int m = m0 + lr;
            float va = 0.f;
            if (m < M && k < K)
                va = (k < K1) ? A1[(size_t)m * lda1 + k]
                              : A2[(size_t)m * lda2 + (k - K1)];
            As[lk0 + i][lr] = va;
            int nn = n0 + lr;
            float vb = 0.f;
            if (nn < N && k < K) vb = Bm[(size_t)nn * ldb + k];
            Bs[lk0 + i][lr] = vb;
        }
        __syncthreads();
        #pragma unroll
        for (int kk = 0; kk < BK; ++kk) {
            const float4 a4 = *(const float4*)&As[kk][ty << 2];
            const float4 b4 = *(const float4*)&Bs[kk][tx << 2];
            const float a[4] = {a4.x, a4.y, a4.z, a4.w};
            const float b[4] = {b4.x, b4.y, b4.z, b4.w};
            #pragma unroll
            for (int i = 0; i < 4; ++i)
                #pragma unroll
                for (int j = 0; j < 4; ++j)
                    acc[i][j] = fmaf(a[i], b[j], acc[i][j]);
        }
        __syncthreads();
    }

    if (MODE == 0) {
        #pragma unroll
        for (int i = 0; i < 4; ++i) {
            int m = m0 + (ty << 2) + i;
            if (m >= M) continue;
            #pragma unroll
            for (int j = 0; j < 4; ++j) {
                int nn = n0 + (tx << 2) + j;
                if (nn < N) C[(size_t)m * ldc + nn] = acc[i][j] + (bias ? bias[nn] : 0.f);
            }
        }
    } else {
        const int jj = (n0 >> 2) + tx;  // hidden unit 0..255
        #pragma unroll
        for (int i = 0; i < 4; ++i) {
            int m = m0 + (ty << 2) + i;
            if (m >= M) continue;
            float rp = acc[i][0] + bias[(jj << 2) + 0];
            float zp = acc[i][1] + bias[(jj << 2) + 1];
            float xn = acc[i][2] + bias[(jj << 2) + 2];
            float hn = acc[i][3] + bias[(jj << 2) + 3];
            float r = sigmoidf_(rp);
            float z = sigmoidf_(zp);
            float ng = tanhf(xn + r * hn);
            float hprev = h_in[(size_t)m * H_ + jj];
            float hnew = (1.f - z) * ng + z * hprev;
            C[(size_t)m * H_ + jj] = hnew;
            if (t == len[m] - 1) his_last[(size_t)m * H_ + jj] = hnew;
        }
    }
}

// ---------------------------------------------------------------------------
// Build interleaved gate weight matrix Wbig (1024 x 384) + bias_big (1024)
// row 4*j+0: [w_ih_r[j] | w_hh_r[j]]        bias b_ih[j]+b_hh[j]
// row 4*j+1: [w_ih_z[j] | w_hh_z[j]]        bias b_ih[256+j]+b_hh[256+j]
// row 4*j+2: [w_ih_n[j] | 0        ]        bias b_ih[512+j]
// row 4*j+3: [0         | w_hh_n[j]]        bias b_hh[512+j]
// ---------------------------------------------------------------------------
__global__ void prep_wbig(const float* __restrict__ w_ih, const float* __restrict__ w_hh,
                          const float* __restrict__ b_ih, const float* __restrict__ b_hh,
                          float* __restrict__ Wbig, float* __restrict__ bias_big)
{
    int idx = blockIdx.x * 256 + threadIdx.x;
    if (idx >= 1024 * 384) return;
    int row = idx / 384, k = idx % 384;
    int j = row >> 2, c = row & 3;
    float v = 0.f;
    if (c == 0)      v = (k < 128) ? w_ih[j * 128 + k]          : w_hh[j * 256 + (k - 128)];
    else if (c == 1) v = (k < 128) ? w_ih[(256 + j) * 128 + k]  : w_hh[(256 + j) * 256 + (k - 128)];
    else if (c == 2) v = (k < 128) ? w_ih[(512 + j) * 128 + k]  : 0.f;
    else             v = (k < 128) ? 0.f                         : w_hh[(512 + j) * 256 + (k - 128)];
    Wbig[idx] = v;
    if (k == 0) {
        float bb;
        if (c == 0)      bb = b_ih[j] + b_hh[j];
        else if (c == 1) bb = b_ih[256 + j] + b_hh[256 + j];
        else if (c == 2) bb = b_ih[512 + j];
        else             bb = b_hh[512 + j];
        bias_big[row] = bb;
    }
}

// ---------------------------------------------------------------------------
// Intra GRU, register-resident recurrent weights.
// Grid: 16 blocks (one per batch) x 768 threads (one per w_hh row).
// xw (1024,768) = intra_x @ w_ih^T + b_ih is precomputed by a GEMM.
// Each thread holds its 256-float w_hh row in VGPRs (static-indexed, fully
// unrolled). Per step: 256 reg-FMAs (h broadcast from LDS), LDS gather of the
// 3 gate pre-activations, combine in threads 0..255, 2 barriers.
// ---------------------------------------------------------------------------
__global__ __launch_bounds__(768) void intra_gru_reg(
    const float* __restrict__ w_hh, const float* __restrict__ b_hh,
    const float* __restrict__ xw,   // (1024, 768): [xr | xz | xn] per (b,t)
    float* __restrict__ ih)         // (1024, 256)
{
    __shared__ __align__(16) float hs[H_];
    __shared__ float ghs[768];
    const int b = blockIdx.x, tid = threadIdx.x;

    // one-time: weight row -> registers
    float w[256];
    const float4* wrow = (const float4*)(w_hh + (size_t)tid * 256);
    #pragma unroll
    for (int k4 = 0; k4 < 64; ++k4) {
        float4 v = wrow[k4];
        w[4 * k4 + 0] = v.x; w[4 * k4 + 1] = v.y;
        w[4 * k4 + 2] = v.z; w[4 * k4 + 3] = v.w;
    }
    const float bhh = b_hh[tid];
    if (tid < H_) hs[tid] = 0.f;
    __syncthreads();

    for (int t = 0; t < S_; ++t) {
        // prefetch xw early; consumed after the FMA chain (hides L2 latency)
        float xr = 0.f, xz = 0.f, xn = 0.f;
        if (tid < H_) {
            const float* xp = xw + ((size_t)b * S_ + t) * 768;
            xr = xp[tid]; xz = xp[256 + tid]; xn = xp[512 + tid];
        }
        float a0 = bhh, a1 = 0.f, a2 = 0.f, a3 = 0.f;
        #pragma unroll
        for (int k4 = 0; k4 < 64; ++k4) {
            float4 hv = *(const float4*)&hs[4 * k4];   // same addr all lanes: broadcast
            a0 = fmaf(hv.x, w[4 * k4 + 0], a0);
            a1 = fmaf(hv.y, w[4 * k4 + 1], a1);
            a2 = fmaf(hv.z, w[4 * k4 + 2], a2);
            a3 = fmaf(hv.w, w[4 * k4 + 3], a3);
        }
        ghs[tid] = (a0 + a1) + (a2 + a3);
        __syncthreads();
        if (tid < H_) {
            float gr = ghs[tid], gz = ghs[256 + tid], gn = ghs[512 + tid];
            float r = sigmoidf_(xr + gr);
            float z = sigmoidf_(xz + gz);
            float n = tanhf(xn + r * gn);
            float hnew = (1.f - z) * n + z * hs[tid];
            hs[tid] = hnew;
            ih[((size_t)b * S_ + t) * H_ + tid] = hnew;
        }
        __syncthreads();
    }
}

// ---------------------------------------------------------------------------
// Concat / pack kernels
// ---------------------------------------------------------------------------
__global__ void concat_mrv(const float* __restrict__ hl, const float* __restrict__ ir,
                           float* __restrict__ Mrv)
{
    int idx = blockIdx.x * 256 + threadIdx.x;          // BSR_*384
    if (idx >= BSR_ * 384) return;
    int c = idx % 384, pr = idx / 384;
    Mrv[idx] = (c < 256) ? hl[(size_t)pr * 256 + c] : ir[(size_t)pr * 128 + (c - 256)];
}

__global__ void concat_mpv(const float* __restrict__ ihf, const float* __restrict__ x,
                           float* __restrict__ mpv)
{
    int idx = blockIdx.x * 256 + threadIdx.x;          // BS_*384
    if (idx >= BS_ * 384) return;
    int c = idx % 384, p = idx / 384;
    float v = 0.f;
    if (c < 256)      v = ihf[(size_t)p * 256 + c];
    else if (c < 383) v = x[(size_t)p * 128 + (c - 256)];
    mpv[idx] = v;
}

__global__ void concat_ihp(const float* __restrict__ ihf, const float* __restrict__ x,
                           float* __restrict__ ihp)
{
    int idx = blockIdx.x * 256 + threadIdx.x;          // BS_*260
    if (idx >= BS_ * 260) return;
    int c = idx % 260, p = idx / 260;
    float v = 0.f;
    if (c < 256)       v = ihf[(size_t)p * 256 + c];
    else if (c == 256) v = x[(size_t)p * 128 + 127];
    ihp[idx] = v;
}

__global__ void combine_feat(const float* __restrict__ vv, const float* __restrict__ vh,
                             const float* __restrict__ ihf, const float* __restrict__ x,
                             const float* __restrict__ wr, float* __restrict__ feat)
{
    int idx = blockIdx.x * 256 + threadIdx.x;          // BS_*640
    if (idx >= BS_ * 640) return;
    int c = idx % 640, p = idx / 640;
    float e0 = __expf(wr[0]), e1 = __expf(wr[1]);
    float w0 = e0 / (e0 + e1), w1 = e1 / (e0 + e1);
    float v = 0.f;
    if (c < 256)      v = w0 * vv[(size_t)p * 256 + c] + w1 * vh[(size_t)p * 256 + c];
    else if (c < 512) v = ihf[(size_t)p * 256 + (c - 256)];
    else if (c < 639) v = x[(size_t)p * 128 + (c - 512)];
    feat[idx] = v;
}

// ---------------------------------------------------------------------------
// v_v attention: R=6 keys, 1 query per (p, head). One wave per (p, head).
// ---------------------------------------------------------------------------
__global__ __launch_bounds__(256) void attn_vv(
    const float* __restrict__ q,   // (1024,256)
    const float* __restrict__ k,   // (6144,256)
    const float* __restrict__ v,   // (6144,256)
    float* __restrict__ o)         // (1024,256)
{
    int wid = (blockIdx.x * 256 + threadIdx.x) >> 6;   // 0..2047
    int lane = threadIdx.x & 63;
    int p = wid >> 1, head = wid & 1;
    int d0 = head * 128 + lane * 2;
    const float* qp = q + (size_t)p * 256 + d0;
    float q0 = qp[0], q1 = qp[1];
    float sc[R_];
    #pragma unroll
    for (int r = 0; r < R_; ++r) {
        const float* kp = k + (size_t)(p * R_ + r) * 256 + d0;
        float s = q0 * kp[0] + q1 * kp[1];
        #pragma unroll
        for (int off = 32; off; off >>= 1) s += __shfl_xor(s, off, 64);
        sc[r] = s * 0.08838834764831845f;   // 1/sqrt(128)
    }
    float mx = sc[0];
    #pragma unroll
    for (int r = 1; r < R_; ++r) mx = fmaxf(mx, sc[r]);
    float sum = 0.f;
    #pragma unroll
    for (int r = 0; r < R_; ++r) { sc[r] = __expf(sc[r] - mx); sum += sc[r]; }
    float inv = 1.f / sum;
    float o0 = 0.f, o1 = 0.f;
    #pragma unroll
    for (int r = 0; r < R_; ++r) {
        const float* vp = v + (size_t)(p * R_ + r) * 256 + d0;
        o0 += sc[r] * vp[0];
        o1 += sc[r] * vp[1];
    }
    o[(size_t)p * 256 + d0]     = o0 * inv;
    o[(size_t)p * 256 + d0 + 1] = o1 * inv;
}

// ---------------------------------------------------------------------------
// v_h attention: causal 64x64 per (b, head). One wave per (b, head, q-row).
// ---------------------------------------------------------------------------
__global__ __launch_bounds__(256) void attn_vh(
    const float* __restrict__ q,   // (1024,256)
    const float* __restrict__ k,   // (1024,256)
    const float* __restrict__ v,   // (1024,256)
    float* __restrict__ o)         // (1024,256)
{
    __shared__ float ps[4][64];
    int widb = threadIdx.x >> 6;
    int wid = blockIdx.x * 4 + widb;                   // 0..2047
    int lane = threadIdx.x & 63;
    int b = wid >> 7;
    int rem = wid & 127;
    int head = rem >> 6;
    int qi = rem & 63;
    const float* qrow = q + ((size_t)b * 64 + qi) * 256 + head * 128;
    const float* krow = k + ((size_t)b * 64 + lane) * 256 + head * 128;
    float sA = 0.f, sB = 0.f;
    for (int d = 0; d < 128; d += 2) {
        sA = fmaf(qrow[d],     krow[d],     sA);
        sB = fmaf(qrow[d + 1], krow[d + 1], sB);
    }
    float s = (sA + sB) * 0.08838834764831845f;
    bool valid = (lane <= qi);
    float smax = valid ? s : -1e30f;
    #pragma unroll
    for (int off = 32; off; off >>= 1) smax = fmaxf(smax, __shfl_xor(smax, off, 64));
    float e = valid ? __expf(s - smax) : 0.f;
    float ssum = e;
    #pragma unroll
    for (int off = 32; off; off >>= 1) ssum += __shfl_xor(ssum, off, 64);
    float pv = e / ssum;
    ps[widb][lane] = pv;
    __syncthreads();
    float o0 = 0.f, o1 = 0.f;
    for (int j = 0; j <= qi; ++j) {
        float pj = ps[widb][j];
        const float* vrow = v + ((size_t)b * 64 + j) * 256 + head * 128;
        o0 = fmaf(pj, vrow[lane],      o0);
        o1 = fmaf(pj, vrow[lane + 64], o1);
    }
    o[((size_t)b * 64 + qi) * 256 + head * 128 + lane]      = o0;
    o[((size_t)b * 64 + qi) * 256 + head * 128 + lane + 64] = o1;
}

// ---------------------------------------------------------------------------
extern "C" void kernel_launch(void* const* d_in, const int* in_sizes, int n_in,
                              void* d_out, int out_size, void* d_ws, size_t ws_size,
                              hipStream_t stream)
{
    const float* intra_x   = (const float*)d_in[0];
    const float* inter_his = (const float*)d_in[1];
    const float* inter_r   = (const float*)d_in[2];
    const int*   inter_len = (const int*)  d_in[4];
    const float* w_ih = (const float*)d_in[5];
    const float* w_hh = (const float*)d_in[6];
    const float* b_ih = (const float*)d_in[7];
    const float* b_hh = (const float*)d_in[8];
    const float* iq_w = (const float*)d_in[9];
    const float* iq_b = (const float*)d_in[10];
    const float* ik_w = (const float*)d_in[11];
    const float* ik_b = (const float*)d_in[12];
    const float* iv_w = (const float*)d_in[13];
    const float* iv_b = (const float*)d_in[14];
    const float* io_w = (const float*)d_in[15];
    const float* io_b = (const float*)d_in[16];
    const float* aq_w = (const float*)d_in[17];
    const float* aq_b = (const float*)d_in[18];
    const float* ak_w = (const float*)d_in[19];
    const float* ak_b = (const float*)d_in[20];
    const float* av_w = (const float*)d_in[21];
    const float* av_b = (const float*)d_in[22];
    const float* ao_w = (const float*)d_in[23];
    const float* ao_b = (const float*)d_in[24];
    const float* wr   = (const float*)d_in[25];
    const float* ln_w = (const float*)d_in[26];
    const float* ln_b = (const float*)d_in[27];
    float* out = (float*)d_out;

    char* ws = (char*)d_ws;
    size_t off = 0;
    auto alloc = [&](size_t bytes) -> float* {
        char* p = ws + off;
        off += (bytes + 255) & ~(size_t)255;
        return (float*)p;
    };
    float* Wbig    = alloc(1024 * 384 * 4);
    float* biasb   = alloc(1024 * 4);
    float* h_ping  = alloc((size_t)BSR_ * H_ * 4);
    float* h_pong  = alloc((size_t)BSR_ * H_ * 4);
    float* hislast = alloc((size_t)BSR_ * H_ * 4);
    float* intraH  = alloc((size_t)BS_ * H_ * 4);
    float* xwI     = alloc((size_t)BS_ * 768 * 4);
    float* Mrv     = alloc((size_t)BSR_ * 384 * 4);
    float* mpv     = alloc((size_t)BS_ * 384 * 4);
    float* qbuf    = alloc((size_t)BS_ * 256 * 4);
    float* kbuf    = alloc((size_t)BSR_ * 256 * 4);
    float* vbuf    = alloc((size_t)BSR_ * 256 * 4);
    float* attno   = alloc((size_t)BS_ * 256 * 4);
    float* vv      = alloc((size_t)BS_ * 256 * 4);
    float* ihp     = alloc((size_t)BS_ * 260 * 4);
    float* qa      = alloc((size_t)BS_ * 256 * 4);
    float* ka      = alloc((size_t)BS_ * 256 * 4);
    float* va      = alloc((size_t)BS_ * 256 * 4);
    float* aho     = alloc((size_t)BS_ * 256 * 4);
    float* vhb     = alloc((size_t)BS_ * 256 * 4);
    float* feat    = alloc((size_t)BS_ * 640 * 4);
    (void)ws_size; (void)in_sizes; (void)n_in; (void)out_size;

    auto gemm = [&](const float* A, int lda, const float* Bw, int ldb,
                    const float* bias, float* C, int M, int N, int K) {
        gemm_k<0><<<dim3((M + BM - 1) / BM, (N + BN - 1) / BN), 256, 0, stream>>>(
            A, lda, K, A, 0, Bw, ldb, bias, C, N, M, N, K,
            nullptr, nullptr, nullptr, 0);
    };

    // weight prep
    prep_wbig<<<1536, 256, 0, stream>>>(w_ih, w_hh, b_ih, b_hh, Wbig, biasb);
    hipMemsetAsync(h_ping, 0, (size_t)BSR_ * H_ * 4, stream);

    // intra GRU: x-projection GEMM (time-parallel) + register-resident recurrence
    gemm(intra_x, 128, w_ih, 128, b_ih, xwI, BS_, 768, 128);
    intra_gru_reg<<<B_, 768, 0, stream>>>(w_hh, b_hh, xwI, intraH);

    // inter GRU: 24 fused GEMM+gate steps
    for (int t = 0; t < L_; ++t) {
        const float* hin = (t & 1) ? h_pong : h_ping;
        float* hout      = (t & 1) ? h_ping : h_pong;
        gemm_k<1><<<dim3(BSR_ / BM, 1024 / BN), 256, 0, stream>>>(
            inter_his + (size_t)t * D_, L_ * D_, D_, hin, H_,
            Wbig, 384, biasb, hout, H_, BSR_, 1024, 384,
            hin, hislast, inter_len, t);
    }

    // v_v branch
    concat_mrv<<<(BSR_ * 384 + 255) / 256, 256, 0, stream>>>(hislast, inter_r, Mrv);
    concat_mpv<<<(BS_ * 384 + 255) / 256, 256, 0, stream>>>(intraH, intra_x, mpv);
    gemm(mpv, 384, iq_w, 383, iq_b, qbuf, BS_, 256, 383);
    gemm(Mrv, 384, ik_w, 383, ik_b, kbuf, BSR_, 256, 383);
    gemm(Mrv, 384, iv_w, 384, iv_b, vbuf, BSR_, 256, 384);
    attn_vv<<<512, 256, 0, stream>>>(qbuf, kbuf, vbuf, attno);
    gemm(attno, 256, io_w, 256, io_b, vv, BS_, 256, 256);

    // v_h branch
    concat_ihp<<<(BS_ * 260 + 255) / 256, 256, 0, stream>>>(intraH, intra_x, ihp);
    gemm(intra_x, 128, aq_w, 127, aq_b, qa, BS_, 256, 127);
    gemm(intra_x, 128, ak_w, 127, ak_b, ka, BS_, 256, 127);
    gemm(ihp, 260, av_w, 257, av_b, va, BS_, 256, 257);
    attn_vh<<<512, 256, 0, stream>>>(qa, ka, va, aho);
    gemm(aho, 256, ao_w, 256, ao_b, vhb, BS_, 256, 256);

    // combine + final projection
    combine_feat<<<(BS_ * 640 + 255) / 256, 256, 0, stream>>>(vv, vhb, intraH, intra_x, wr, feat);
    gemm(feat, 640, ln_w, 639, ln_b, out, BS_, 256, 639);
}

// Round 4
// 2364.953 us; speedup vs baseline: 2.6788x; 2.1524x over previous
//
#include <hip/hip_runtime.h>
#include <hip/hip_bf16.h>
#include <math.h>

// Shapes
#define B_  16
#define S_  64
#define R_  6
#define L_  24
#define D_  128
#define H_  256
#define BS_   1024    // B*S
#define BSR_  6144    // B*S*R

typedef __attribute__((ext_vector_type(8))) short short8;
typedef __attribute__((ext_vector_type(4))) float f32x4;

__device__ __forceinline__ float sigmoidf_(float x) { return 1.f / (1.f + __expf(-x)); }

// RNE float->bf16 helpers
__device__ __forceinline__ unsigned short f2bf(float f) {
    unsigned int u = __float_as_uint(f);
    u = (u + 0x7fff + ((u >> 16) & 1)) >> 16;
    return (unsigned short)u;
}
__device__ __forceinline__ unsigned int pack2(float a, float b) {
    unsigned int ua = __float_as_uint(a), ub = __float_as_uint(b);
    ua = (ua + 0x7fff + ((ua >> 16) & 1)) >> 16;
    ub = (ub + 0x7fff + ((ub >> 16) & 1)) & 0xffff0000u;
    return (ua & 0xffffu) | ub;
}

// ---------------------------------------------------------------------------
// fp32 tiled GEMM (small projections): C[m,n] = bias[n] + sum_k A(m,k)*B[n*ldb+k]
// A(m,k) = (k < K1) ? A1[m*lda1+k] : A2[m*lda2+(k-K1)]
// ---------------------------------------------------------------------------
#define BM 64
#define BN 64
#define BK 16

__global__ __launch_bounds__(256) void gemm_k(
    const float* __restrict__ A1, int lda1, int K1,
    const float* __restrict__ A2, int lda2,
    const float* __restrict__ Bm, int ldb,
    const float* __restrict__ bias,
    float* __restrict__ C, int ldc,
    int M, int N, int K)
{
    __shared__ float As[BK][BM + 4];
    __shared__ float Bs[BK][BN + 4];
    const int tid = threadIdx.x;
    const int m0 = blockIdx.x * BM;
    const int n0 = blockIdx.y * BN;
    const int tx = tid & 15, ty = tid >> 4;
    const int lr  = tid >> 2;
    const int lk0 = (tid & 3) << 2;
    float acc[4][4] = {};

    for (int k0 = 0; k0 < K; k0 += BK) {
        #pragma unroll
        for (int i = 0; i < 4; ++i) {
            int k = k0 + lk0 + i;
            int m = m0 + lr;
            float va = 0.f;
            if (m < M && k < K)
                va = (k < K1) ? A1[(size_t)m * lda1 + k]
                              : A2[(size_t)m * lda2 + (k - K1)];
            As[lk0 + i][lr] = va;
            int nn = n0 + lr;
            float vb = 0.f;
            if (nn < N && k < K) vb = Bm[(size_t)nn * ldb + k];
            Bs[lk0 + i][lr] = vb;
        }
        __syncthreads();
        #pragma unroll
        for (int kk = 0; kk < BK; ++kk) {
            const float4 a4 = *(const float4*)&As[kk][ty << 2];
            const float4 b4 = *(const float4*)&Bs[kk][tx << 2];
            const float a[4] = {a4.x, a4.y, a4.z, a4.w};
            const float b[4] = {b4.x, b4.y, b4.z, b4.w};
            #pragma unroll
            for (int i = 0; i < 4; ++i)
                #pragma unroll
                for (int j = 0; j < 4; ++j)
                    acc[i][j] = fmaf(a[i], b[j], acc[i][j]);
        }
        __syncthreads();
    }
    #pragma unroll
    for (int i = 0; i < 4; ++i) {
        int m = m0 + (ty << 2) + i;
        if (m >= M) continue;
        #pragma unroll
        for (int j = 0; j < 4; ++j) {
            int nn = n0 + (tx << 2) + j;
            if (nn < N) C[(size_t)m * ldc + nn] = acc[i][j] + bias[nn];
        }
    }
}

// ---------------------------------------------------------------------------
// Wbig bf16 (1024 x 384) + biasb fp32 (1024), interleaved gate quadruples:
// row 4u+0: [w_ih_r[u] | w_hh_r[u]]  bias bihr+bhhr
// row 4u+1: [w_ih_z[u] | w_hh_z[u]]  bias bihz+bhhz
// row 4u+2: [w_ih_n[u] | 0       ]   bias bihn
// row 4u+3: [0         | w_hh_n[u]]  bias bhhn
// ---------------------------------------------------------------------------
__global__ void prep_wbig(const float* __restrict__ w_ih, const float* __restrict__ w_hh,
                          const float* __restrict__ b_ih, const float* __restrict__ b_hh,
                          unsigned short* __restrict__ Wbg, float* __restrict__ biasb)
{
    int idx = blockIdx.x * 256 + threadIdx.x;
    if (idx >= 1024 * 384) return;
    int row = idx / 384, k = idx % 384;
    int j = row >> 2, c = row & 3;
    float v = 0.f;
    if (c == 0)      v = (k < 128) ? w_ih[j * 128 + k]          : w_hh[j * 256 + (k - 128)];
    else if (c == 1) v = (k < 128) ? w_ih[(256 + j) * 128 + k]  : w_hh[(256 + j) * 256 + (k - 128)];
    else if (c == 2) v = (k < 128) ? w_ih[(512 + j) * 128 + k]  : 0.f;
    else             v = (k < 128) ? 0.f                         : w_hh[(512 + j) * 256 + (k - 128)];
    Wbg[idx] = f2bf(v);
    if (k == 0) {
        float bb;
        if (c == 0)      bb = b_ih[j] + b_hh[j];
        else if (c == 1) bb = b_ih[256 + j] + b_hh[256 + j];
        else if (c == 2) bb = b_ih[512 + j];
        else             bb = b_hh[512 + j];
        biasb[row] = bb;
    }
}

// ---------------------------------------------------------------------------
// Inter-GRU step: C(6144x1024) = [x_t | h_t](bf16) @ Wbig^T + fused gate epilogue.
// MFMA 16x16x32 bf16; tile 128x128, 4 waves (2x2), BK=32, dbuf LDS, 80B rows.
// ---------------------------------------------------------------------------
__global__ __launch_bounds__(256) void gru_step(
    const float* __restrict__ his,       // (6144,24,128) fp32
    const unsigned short* __restrict__ Wbg,   // (1024,384) bf16
    const float* __restrict__ biasb,     // (1024)
    const unsigned short* __restrict__ hcur,  // (6144,256) bf16
    unsigned short* __restrict__ hnxt,        // (6144,256) bf16
    float* __restrict__ hfp,             // (6144,256) fp32, in-place state
    float* __restrict__ his_last,        // (6144,256) fp32
    const int* __restrict__ len, int t)
{
    __shared__ __align__(16) char lds[40960];
    const int tid = threadIdx.x;
    const int lane = tid & 63, wv = tid >> 6;
    const int wm = wv >> 1, wn = wv & 1;
    const int l15 = lane & 15, l4 = lane >> 4;
    const int m0 = blockIdx.x * 128, n0 = blockIdx.y * 128;

    // staging: thread covers chunks {tid, tid+256}; chunk c -> row c>>2, kslot c&3 (8 bf16 = 16B)
    const int ar1 = tid >> 2,        ak1 = tid & 3;
    const int ar2 = (tid + 256) >> 2, ak2 = (tid + 256) & 3;

    const int AB0 = 0, AB1 = 10240, WB0 = 20480, WB1 = 30720;  // byte bases

    f32x4 acc[4][4] = {};

    auto loadA = [&](int ks, int row, int kc) -> uint4 {
        if (ks < 4) {   // x-part from fp32 inter_his, convert to bf16 on the fly
            const float* p = his + ((size_t)(m0 + row) * 24 + t) * 128 + ks * 32 + kc * 8;
            float4 f0 = *(const float4*)p;
            float4 f1 = *(const float4*)(p + 4);
            uint4 r;
            r.x = pack2(f0.x, f0.y); r.y = pack2(f0.z, f0.w);
            r.z = pack2(f1.x, f1.y); r.w = pack2(f1.z, f1.w);
            return r;
        }
        return *(const uint4*)(hcur + (size_t)(m0 + row) * 256 + (ks - 4) * 32 + kc * 8);
    };
    auto loadW = [&](int ks, int row, int kc) -> uint4 {
        return *(const uint4*)(Wbg + (size_t)(n0 + row) * 384 + ks * 32 + kc * 8);
    };
    auto stq = [&](int base, int row, int kc, uint4 v) {
        *(uint4*)(lds + base + row * 80 + kc * 16) = v;
    };

    // prologue: stage k-step 0 into buffer 0
    {
        uint4 a1 = loadA(0, ar1, ak1), a2 = loadA(0, ar2, ak2);
        uint4 w1 = loadW(0, ar1, ak1), w2 = loadW(0, ar2, ak2);
        stq(AB0, ar1, ak1, a1); stq(AB0, ar2, ak2, a2);
        stq(WB0, ar1, ak1, w1); stq(WB0, ar2, ak2, w2);
    }
    __syncthreads();

    for (int ks = 0; ks < 12; ++ks) {
        const int cb = ks & 1;
        uint4 a1, a2, w1, w2;
        if (ks < 11) {
            a1 = loadA(ks + 1, ar1, ak1); a2 = loadA(ks + 1, ar2, ak2);
            w1 = loadW(ks + 1, ar1, ak1); w2 = loadW(ks + 1, ar2, ak2);
        }
        const int ab = cb ? AB1 : AB0;
        const int wb = cb ? WB1 : WB0;
        short8 af[4], bfr[4];
        #pragma unroll
        for (int i = 0; i < 4; ++i) {
            af[i]  = *(const short8*)(lds + ab + (wm * 64 + i * 16 + l15) * 80 + l4 * 16);
            bfr[i] = *(const short8*)(lds + wb + (wn * 64 + i * 16 + l15) * 80 + l4 * 16);
        }
        #pragma unroll
        for (int i = 0; i < 4; ++i)
            #pragma unroll
            for (int j = 0; j < 4; ++j)
                acc[i][j] = __builtin_amdgcn_mfma_f32_16x16x32_bf16(af[i], bfr[j], acc[i][j], 0, 0, 0);
        if (ks < 11) {
            const int nab = cb ? AB0 : AB1;
            const int nwb = cb ? WB0 : WB1;
            stq(nab, ar1, ak1, a1); stq(nab, ar2, ak2, a2);
            stq(nwb, ar1, ak1, w1); stq(nwb, ar2, ak2, w2);
        }
        __syncthreads();
    }

    // epilogue: C/D frag col = lane&15 (= 4u+c), rows = (lane>>4)*4 + j.
    // lanes 4u+{0,1,2,3} hold (r,z,xn,hn) pre-activations for unit u, same rows.
    #pragma unroll
    for (int mi = 0; mi < 4; ++mi) {
        const int mb = m0 + wm * 64 + mi * 16 + l4 * 4;
        #pragma unroll
        for (int ni = 0; ni < 4; ++ni) {
            const int colg = n0 + wn * 64 + ni * 16 + l15;
            const float bs = biasb[colg];
            #pragma unroll
            for (int j = 0; j < 4; ++j) {
                float s  = acc[mi][ni][j] + bs;
                float s1 = __shfl_xor(s, 1);
                float s2 = __shfl_xor(s, 2);
                float s3 = __shfl_xor(s, 3);
                if ((lane & 3) == 0) {
                    const int m = mb + j;
                    const int u = colg >> 2;
                    float r  = sigmoidf_(s);
                    float z  = sigmoidf_(s1);
                    float ng = tanhf(s2 + r * s3);
                    float hp = hfp[(size_t)m * 256 + u];
                    float hn = (1.f - z) * ng + z * hp;
                    hfp[(size_t)m * 256 + u] = hn;
                    hnxt[(size_t)m * 256 + u] = f2bf(hn);
                    if (t == len[m] - 1) his_last[(size_t)m * 256 + u] = hn;
                }
            }
        }
    }
}

// ---------------------------------------------------------------------------
// Intra GRU: 16 blocks x 768 threads; w_hh row bf16-packed in 128 VGPRs.
// __launch_bounds__(768,3): 12-wave block = 3 waves/EU -> VGPR budget ~682.
// ---------------------------------------------------------------------------
__global__ __launch_bounds__(768, 3) void intra_gru_reg(
    const float* __restrict__ w_hh, const float* __restrict__ b_hh,
    const float* __restrict__ xw,   // (1024,768): [xr|xz|xn] per (b,t)
    float* __restrict__ ih)         // (1024,256)
{
    __shared__ __align__(8) float hs[H_];
    __shared__ float ghs[768];
    const int b = blockIdx.x, tid = threadIdx.x;

    unsigned int w2[128];
    const float4* wrow = (const float4*)(w_hh + (size_t)tid * 256);
    #pragma unroll
    for (int i = 0; i < 64; ++i) {
        float4 v = wrow[i];
        w2[2 * i]     = pack2(v.x, v.y);
        w2[2 * i + 1] = pack2(v.z, v.w);
    }
    const float bhh = b_hh[tid];
    if (tid < H_) hs[tid] = 0.f;
    __syncthreads();

    for (int t = 0; t < S_; ++t) {
        float xr = 0.f, xz = 0.f, xn = 0.f;
        if (tid < H_) {
            const float* xp = xw + ((size_t)b * S_ + t) * 768;
            xr = xp[tid]; xz = xp[256 + tid]; xn = xp[512 + tid];
        }
        float a0 = bhh, a1 = 0.f;
        #pragma unroll
        for (int i = 0; i < 128; ++i) {
            float2 hv = *(const float2*)&hs[2 * i];
            a0 = fmaf(hv.x, __uint_as_float(w2[i] << 16), a0);
            a1 = fmaf(hv.y, __uint_as_float(w2[i] & 0xffff0000u), a1);
        }
        ghs[tid] = a0 + a1;
        __syncthreads();
        if (tid < H_) {
            float gr = ghs[tid], gz = ghs[256 + tid], gn = ghs[512 + tid];
            float r = sigmoidf_(xr + gr);
            float z = sigmoidf_(xz + gz);
            float n = tanhf(xn + r * gn);
            float hnew = (1.f - z) * n + z * hs[tid];
            hs[tid] = hnew;
            ih[((size_t)b * S_ + t) * H_ + tid] = hnew;
        }
        __syncthreads();
    }
}

// ---------------------------------------------------------------------------
// Concat / pack kernels
// ---------------------------------------------------------------------------
__global__ void concat_mrv(const float* __restrict__ hl, const float* __restrict__ ir,
                           float* __restrict__ Mrv)
{
    int idx = blockIdx.x * 256 + threadIdx.x;          // BSR_*384
    if (idx >= BSR_ * 384) return;
    int c = idx % 384, pr = idx / 384;
    Mrv[idx] = (c < 256) ? hl[(size_t)pr * 256 + c] : ir[(size_t)pr * 128 + (c - 256)];
}

__global__ void concat_mpv(const float* __restrict__ ihf, const float* __restrict__ x,
                           float* __restrict__ mpv)
{
    int idx = blockIdx.x * 256 + threadIdx.x;          // BS_*384
    if (idx >= BS_ * 384) return;
    int c = idx % 384, p = idx / 384;
    float v = 0.f;
    if (c < 256)      v = ihf[(size_t)p * 256 + c];
    else if (c < 383) v = x[(size_t)p * 128 + (c - 256)];
    mpv[idx] = v;
}

__global__ void concat_ihp(const float* __restrict__ ihf, const float* __restrict__ x,
                           float* __restrict__ ihp)
{
    int idx = blockIdx.x * 256 + threadIdx.x;          // BS_*260
    if (idx >= BS_ * 260) return;
    int c = idx % 260, p = idx / 260;
    float v = 0.f;
    if (c < 256)       v = ihf[(size_t)p * 256 + c];
    else if (c == 256) v = x[(size_t)p * 128 + 127];
    ihp[idx] = v;
}

__global__ void combine_feat(const float* __restrict__ vv, const float* __restrict__ vh,
                             const float* __restrict__ ihf, const float* __restrict__ x,
                             const float* __restrict__ wr, float* __restrict__ feat)
{
    int idx = blockIdx.x * 256 + threadIdx.x;          // BS_*640
    if (idx >= BS_ * 640) return;
    int c = idx % 640, p = idx / 640;
    float e0 = __expf(wr[0]), e1 = __expf(wr[1]);
    float w0 = e0 / (e0 + e1), w1 = e1 / (e0 + e1);
    float v = 0.f;
    if (c < 256)      v = w0 * vv[(size_t)p * 256 + c] + w1 * vh[(size_t)p * 256 + c];
    else if (c < 512) v = ihf[(size_t)p * 256 + (c - 256)];
    else if (c < 639) v = x[(size_t)p * 128 + (c - 512)];
    feat[idx] = v;
}

// ---------------------------------------------------------------------------
// v_v attention: R=6 keys, 1 query per (p, head). One wave per (p, head).
// ---------------------------------------------------------------------------
__global__ __launch_bounds__(256) void attn_vv(
    const float* __restrict__ q, const float* __restrict__ k,
    const float* __restrict__ v, float* __restrict__ o)
{
    int wid = (blockIdx.x * 256 + threadIdx.x) >> 6;
    int lane = threadIdx.x & 63;
    int p = wid >> 1, head = wid & 1;
    int d0 = head * 128 + lane * 2;
    const float* qp = q + (size_t)p * 256 + d0;
    float q0 = qp[0], q1 = qp[1];
    float sc[R_];
    #pragma unroll
    for (int r = 0; r < R_; ++r) {
        const float* kp = k + (size_t)(p * R_ + r) * 256 + d0;
        float s = q0 * kp[0] + q1 * kp[1];
        #pragma unroll
        for (int off = 32; off; off >>= 1) s += __shfl_xor(s, off, 64);
        sc[r] = s * 0.08838834764831845f;
    }
    float mx = sc[0];
    #pragma unroll
    for (int r = 1; r < R_; ++r) mx = fmaxf(mx, sc[r]);
    float sum = 0.f;
    #pragma unroll
    for (int r = 0; r < R_; ++r) { sc[r] = __expf(sc[r] - mx); sum += sc[r]; }
    float inv = 1.f / sum;
    float o0 = 0.f, o1 = 0.f;
    #pragma unroll
    for (int r = 0; r < R_; ++r) {
        const float* vp = v + (size_t)(p * R_ + r) * 256 + d0;
        o0 += sc[r] * vp[0];
        o1 += sc[r] * vp[1];
    }
    o[(size_t)p * 256 + d0]     = o0 * inv;
    o[(size_t)p * 256 + d0 + 1] = o1 * inv;
}

// ---------------------------------------------------------------------------
// v_h attention: causal 64x64 per (b, head). One wave per (b, head, q-row).
// ---------------------------------------------------------------------------
__global__ __launch_bounds__(256) void attn_vh(
    const float* __restrict__ q, const float* __restrict__ k,
    const float* __restrict__ v, float* __restrict__ o)
{
    __shared__ float ps[4][64];
    int widb = threadIdx.x >> 6;
    int wid = blockIdx.x * 4 + widb;
    int lane = threadIdx.x & 63;
    int b = wid >> 7;
    int rem = wid & 127;
    int head = rem >> 6;
    int qi = rem & 63;
    const float* qrow = q + ((size_t)b * 64 + qi) * 256 + head * 128;
    const float* krow = k + ((size_t)b * 64 + lane) * 256 + head * 128;
    float sA = 0.f, sB = 0.f;
    for (int d = 0; d < 128; d += 2) {
        sA = fmaf(qrow[d],     krow[d],     sA);
        sB = fmaf(qrow[d + 1], krow[d + 1], sB);
    }
    float s = (sA + sB) * 0.08838834764831845f;
    bool valid = (lane <= qi);
    float smax = valid ? s : -1e30f;
    #pragma unroll
    for (int off = 32; off; off >>= 1) smax = fmaxf(smax, __shfl_xor(smax, off, 64));
    float e = valid ? __expf(s - smax) : 0.f;
    float ssum = e;
    #pragma unroll
    for (int off = 32; off; off >>= 1) ssum += __shfl_xor(ssum, off, 64);
    float pv = e / ssum;
    ps[widb][lane] = pv;
    __syncthreads();
    float o0 = 0.f, o1 = 0.f;
    for (int j = 0; j <= qi; ++j) {
        float pj = ps[widb][j];
        const float* vrow = v + ((size_t)b * 64 + j) * 256 + head * 128;
        o0 = fmaf(pj, vrow[lane],      o0);
        o1 = fmaf(pj, vrow[lane + 64], o1);
    }
    o[((size_t)b * 64 + qi) * 256 + head * 128 + lane]      = o0;
    o[((size_t)b * 64 + qi) * 256 + head * 128 + lane + 64] = o1;
}

// ---------------------------------------------------------------------------
extern "C" void kernel_launch(void* const* d_in, const int* in_sizes, int n_in,
                              void* d_out, int out_size, void* d_ws, size_t ws_size,
                              hipStream_t stream)
{
    const float* intra_x   = (const float*)d_in[0];
    const float* inter_his = (const float*)d_in[1];
    const float* inter_r   = (const float*)d_in[2];
    const int*   inter_len = (const int*)  d_in[4];
    const float* w_ih = (const float*)d_in[5];
    const float* w_hh = (const float*)d_in[6];
    const float* b_ih = (const float*)d_in[7];
    const float* b_hh = (const float*)d_in[8];
    const float* iq_w = (const float*)d_in[9];
    const float* iq_b = (const float*)d_in[10];
    const float* ik_w = (const float*)d_in[11];
    const float* ik_b = (const float*)d_in[12];
    const float* iv_w = (const float*)d_in[13];
    const float* iv_b = (const float*)d_in[14];
    const float* io_w = (const float*)d_in[15];
    const float* io_b = (const float*)d_in[16];
    const float* aq_w = (const float*)d_in[17];
    const float* aq_b = (const float*)d_in[18];
    const float* ak_w = (const float*)d_in[19];
    const float* ak_b = (const float*)d_in[20];
    const float* av_w = (const float*)d_in[21];
    const float* av_b = (const float*)d_in[22];
    const float* ao_w = (const float*)d_in[23];
    const float* ao_b = (const float*)d_in[24];
    const float* wr   = (const float*)d_in[25];
    const float* ln_w = (const float*)d_in[26];
    const float* ln_b = (const float*)d_in[27];
    float* out = (float*)d_out;

    char* ws = (char*)d_ws;
    size_t off = 0;
    auto alloc = [&](size_t bytes) -> void* {
        char* p = ws + off;
        off += (bytes + 255) & ~(size_t)255;
        return (void*)p;
    };
    unsigned short* Wbg  = (unsigned short*)alloc((size_t)1024 * 384 * 2);
    float* biasb   = (float*)alloc(1024 * 4);
    unsigned short* hbf0 = (unsigned short*)alloc((size_t)BSR_ * H_ * 2);
    unsigned short* hbf1 = (unsigned short*)alloc((size_t)BSR_ * H_ * 2);
    float* hfp     = (float*)alloc((size_t)BSR_ * H_ * 4);
    float* hislast = (float*)alloc((size_t)BSR_ * H_ * 4);
    float* intraH  = (float*)alloc((size_t)BS_ * H_ * 4);
    float* xwI     = (float*)alloc((size_t)BS_ * 768 * 4);
    float* Mrv     = (float*)alloc((size_t)BSR_ * 384 * 4);
    float* mpv     = (float*)alloc((size_t)BS_ * 384 * 4);
    float* qbuf    = (float*)alloc((size_t)BS_ * 256 * 4);
    float* kbuf    = (float*)alloc((size_t)BSR_ * 256 * 4);
    float* vbuf    = (float*)alloc((size_t)BSR_ * 256 * 4);
    float* attno   = (float*)alloc((size_t)BS_ * 256 * 4);
    float* vv      = (float*)alloc((size_t)BS_ * 256 * 4);
    float* ihp     = (float*)alloc((size_t)BS_ * 260 * 4);
    float* qa      = (float*)alloc((size_t)BS_ * 256 * 4);
    float* ka      = (float*)alloc((size_t)BS_ * 256 * 4);
    float* va      = (float*)alloc((size_t)BS_ * 256 * 4);
    float* aho     = (float*)alloc((size_t)BS_ * 256 * 4);
    float* vhb     = (float*)alloc((size_t)BS_ * 256 * 4);
    float* feat    = (float*)alloc((size_t)BS_ * 640 * 4);
    (void)ws_size; (void)in_sizes; (void)n_in; (void)out_size;

    auto gemm = [&](const float* A, int lda, const float* Bw, int ldb,
                    const float* bias, float* C, int M, int N, int K) {
        gemm_k<<<dim3((M + BM - 1) / BM, (N + BN - 1) / BN), 256, 0, stream>>>(
            A, lda, K, A, 0, Bw, ldb, bias, C, N, M, N, K);
    };

    // weight prep + state init
    prep_wbig<<<1536, 256, 0, stream>>>(w_ih, w_hh, b_ih, b_hh, Wbg, biasb);
    hipMemsetAsync(hbf0, 0, (size_t)BSR_ * H_ * 2, stream);
    hipMemsetAsync(hfp,  0, (size_t)BSR_ * H_ * 4, stream);

    // intra GRU: x-projection GEMM + register-resident recurrence
    gemm(intra_x, 128, w_ih, 128, b_ih, xwI, BS_, 768, 128);
    intra_gru_reg<<<B_, 768, 0, stream>>>(w_hh, b_hh, xwI, intraH);

    // inter GRU: 24 MFMA steps with fused gate epilogue
    for (int t = 0; t < L_; ++t) {
        const unsigned short* hc = (t & 1) ? hbf1 : hbf0;
        unsigned short* hx       = (t & 1) ? hbf0 : hbf1;
        gru_step<<<dim3(BSR_ / 128, 1024 / 128), 256, 0, stream>>>(
            inter_his, Wbg, biasb, hc, hx, hfp, hislast, inter_len, t);
    }

    // v_v branch
    concat_mrv<<<(BSR_ * 384 + 255) / 256, 256, 0, stream>>>(hislast, inter_r, Mrv);
    concat_mpv<<<(BS_ * 384 + 255) / 256, 256, 0, stream>>>(intraH, intra_x, mpv);
    gemm(mpv, 384, iq_w, 383, iq_b, qbuf, BS_, 256, 383);
    gemm(Mrv, 384, ik_w, 383, ik_b, kbuf, BSR_, 256, 383);
    gemm(Mrv, 384, iv_w, 384, iv_b, vbuf, BSR_, 256, 384);
    attn_vv<<<512, 256, 0, stream>>>(qbuf, kbuf, vbuf, attno);
    gemm(attno, 256, io_w, 256, io_b, vv, BS_, 256, 256);

    // v_h branch
    concat_ihp<<<(BS_ * 260 + 255) / 256, 256, 0, stream>>>(intraH, intra_x, ihp);
    gemm(intra_x, 128, aq_w, 127, aq_b, qa, BS_, 256, 127);
    gemm(intra_x, 128, ak_w, 127, ak_b, ka, BS_, 256, 127);
    gemm(ihp, 260, av_w, 257, av_b, va, BS_, 256, 257);
    attn_vh<<<512, 256, 0, stream>>>(qa, ka, va, aho);
    gemm(aho, 256, ao_w, 256, ao_b, vhb, BS_, 256, 256);

    // combine + final projection
    combine_feat<<<(BS_ * 640 + 255) / 256, 256, 0, stream>>>(vv, vhb, intraH, intra_x, wr, feat);
    gemm(feat, 640, ln_w, 639, ln_b, out, BS_, 256, 639);
}

// Round 5
// 2262.522 us; speedup vs baseline: 2.8000x; 1.0453x over previous
//
#include <hip/hip_runtime.h>
#include <hip/hip_bf16.h>
#include <math.h>

// Shapes
#define B_  16
#define S_  64
#define R_  6
#define L_  24
#define D_  128
#define H_  256
#define BS_   1024    // B*S
#define BSR_  6144    // B*S*R

typedef __attribute__((ext_vector_type(8))) short short8;
typedef __attribute__((ext_vector_type(4))) float f32x4;

__device__ __forceinline__ float sigmoidf_(float x) { return 1.f / (1.f + __expf(-x)); }
// fast tanh via __expf (replaces ocml tanhf libcall)
__device__ __forceinline__ float tanhf_(float x) {
    float e = __expf(2.f * x);
    return 1.f - 2.f / (e + 1.f);
}

// RNE float->bf16 helpers
__device__ __forceinline__ unsigned short f2bf(float f) {
    unsigned int u = __float_as_uint(f);
    u = (u + 0x7fff + ((u >> 16) & 1)) >> 16;
    return (unsigned short)u;
}
__device__ __forceinline__ unsigned int pack2(float a, float b) {
    unsigned int ua = __float_as_uint(a), ub = __float_as_uint(b);
    ua = (ua + 0x7fff + ((ua >> 16) & 1)) >> 16;
    ub = (ub + 0x7fff + ((ub >> 16) & 1)) & 0xffff0000u;
    return (ua & 0xffffu) | ub;
}

// bf16-pair FMA from packed uint
#define BF2(hx, hy, w, a0, a1)                                   \
    a0 = fmaf(hx, __uint_as_float((w) << 16), a0);               \
    a1 = fmaf(hy, __uint_as_float((w) & 0xffff0000u), a1);

// ---------------------------------------------------------------------------
// fp32 tiled GEMM (small projections): C[m,n] = bias[n] + sum_k A(m,k)*B[n*ldb+k]
// A(m,k) = (k < K1) ? A1[m*lda1+k] : A2[m*lda2+(k-K1)]
// ---------------------------------------------------------------------------
#define BM 64
#define BN 64
#define BK 16

__global__ __launch_bounds__(256) void gemm_k(
    const float* __restrict__ A1, int lda1, int K1,
    const float* __restrict__ A2, int lda2,
    const float* __restrict__ Bm, int ldb,
    const float* __restrict__ bias,
    float* __restrict__ C, int ldc,
    int M, int N, int K)
{
    __shared__ float As[BK][BM + 4];
    __shared__ float Bs[BK][BN + 4];
    const int tid = threadIdx.x;
    const int m0 = blockIdx.x * BM;
    const int n0 = blockIdx.y * BN;
    const int tx = tid & 15, ty = tid >> 4;
    const int lr  = tid >> 2;
    const int lk0 = (tid & 3) << 2;
    float acc[4][4] = {};

    for (int k0 = 0; k0 < K; k0 += BK) {
        #pragma unroll
        for (int i = 0; i < 4; ++i) {
            int k = k0 + lk0 + i;
            int m = m0 + lr;
            float va = 0.f;
            if (m < M && k < K)
                va = (k < K1) ? A1[(size_t)m * lda1 + k]
                              : A2[(size_t)m * lda2 + (k - K1)];
            As[lk0 + i][lr] = va;
            int nn = n0 + lr;
            float vb = 0.f;
            if (nn < N && k < K) vb = Bm[(size_t)nn * ldb + k];
            Bs[lk0 + i][lr] = vb;
        }
        __syncthreads();
        #pragma unroll
        for (int kk = 0; kk < BK; ++kk) {
            const float4 a4 = *(const float4*)&As[kk][ty << 2];
            const float4 b4 = *(const float4*)&Bs[kk][tx << 2];
            const float a[4] = {a4.x, a4.y, a4.z, a4.w};
            const float b[4] = {b4.x, b4.y, b4.z, b4.w};
            #pragma unroll
            for (int i = 0; i < 4; ++i)
                #pragma unroll
                for (int j = 0; j < 4; ++j)
                    acc[i][j] = fmaf(a[i], b[j], acc[i][j]);
        }
        __syncthreads();
    }
    #pragma unroll
    for (int i = 0; i < 4; ++i) {
        int m = m0 + (ty << 2) + i;
        if (m >= M) continue;
        #pragma unroll
        for (int j = 0; j < 4; ++j) {
            int nn = n0 + (tx << 2) + j;
            if (nn < N) C[(size_t)m * ldc + nn] = acc[i][j] + bias[nn];
        }
    }
}

// ---------------------------------------------------------------------------
// Wbig bf16 (1024 x 384) + biasb fp32 (1024), interleaved gate quadruples
// ---------------------------------------------------------------------------
__global__ void prep_wbig(const float* __restrict__ w_ih, const float* __restrict__ w_hh,
                          const float* __restrict__ b_ih, const float* __restrict__ b_hh,
                          unsigned short* __restrict__ Wbg, float* __restrict__ biasb)
{
    int idx = blockIdx.x * 256 + threadIdx.x;
    if (idx >= 1024 * 384) return;
    int row = idx / 384, k = idx % 384;
    int j = row >> 2, c = row & 3;
    float v = 0.f;
    if (c == 0)      v = (k < 128) ? w_ih[j * 128 + k]          : w_hh[j * 256 + (k - 128)];
    else if (c == 1) v = (k < 128) ? w_ih[(256 + j) * 128 + k]  : w_hh[(256 + j) * 256 + (k - 128)];
    else if (c == 2) v = (k < 128) ? w_ih[(512 + j) * 128 + k]  : 0.f;
    else             v = (k < 128) ? 0.f                         : w_hh[(512 + j) * 256 + (k - 128)];
    Wbg[idx] = f2bf(v);
    if (k == 0) {
        float bb;
        if (c == 0)      bb = b_ih[j] + b_hh[j];
        else if (c == 1) bb = b_ih[256 + j] + b_hh[256 + j];
        else if (c == 2) bb = b_ih[512 + j];
        else             bb = b_hh[512 + j];
        biasb[row] = bb;
    }
}

// w_hh -> bf16, natural row order (768 x 256)
__global__ void prep_whh(const float* __restrict__ w, unsigned short* __restrict__ wb)
{
    int idx = blockIdx.x * 256 + threadIdx.x;
    if (idx < 768 * 256) wb[idx] = f2bf(w[idx]);
}

// ---------------------------------------------------------------------------
// Inter-GRU step: C(6144x1024) = [x_t | h_t](bf16) @ Wbig^T + fused gate epilogue.
// MFMA 16x16x32 bf16; tile 128x128, 4 waves (2x2), BK=32, dbuf LDS, 80B rows.
// ---------------------------------------------------------------------------
__global__ __launch_bounds__(256) void gru_step(
    const float* __restrict__ his,       // (6144,24,128) fp32
    const unsigned short* __restrict__ Wbg,   // (1024,384) bf16
    const float* __restrict__ biasb,     // (1024)
    const unsigned short* __restrict__ hcur,  // (6144,256) bf16
    unsigned short* __restrict__ hnxt,        // (6144,256) bf16
    float* __restrict__ hfp,             // (6144,256) fp32, in-place state
    float* __restrict__ his_last,        // (6144,256) fp32
    const int* __restrict__ len, int t)
{
    __shared__ __align__(16) char lds[40960];
    const int tid = threadIdx.x;
    const int lane = tid & 63, wv = tid >> 6;
    const int wm = wv >> 1, wn = wv & 1;
    const int l15 = lane & 15, l4 = lane >> 4;
    const int m0 = blockIdx.x * 128, n0 = blockIdx.y * 128;

    const int ar1 = tid >> 2,         ak1 = tid & 3;
    const int ar2 = (tid + 256) >> 2, ak2 = (tid + 256) & 3;

    const int AB0 = 0, AB1 = 10240, WB0 = 20480, WB1 = 30720;

    f32x4 acc[4][4] = {};

    auto loadA = [&](int ks, int row, int kc) -> uint4 {
        if (ks < 4) {
            const float* p = his + ((size_t)(m0 + row) * 24 + t) * 128 + ks * 32 + kc * 8;
            float4 f0 = *(const float4*)p;
            float4 f1 = *(const float4*)(p + 4);
            uint4 r;
            r.x = pack2(f0.x, f0.y); r.y = pack2(f0.z, f0.w);
            r.z = pack2(f1.x, f1.y); r.w = pack2(f1.z, f1.w);
            return r;
        }
        return *(const uint4*)(hcur + (size_t)(m0 + row) * 256 + (ks - 4) * 32 + kc * 8);
    };
    auto loadW = [&](int ks, int row, int kc) -> uint4 {
        return *(const uint4*)(Wbg + (size_t)(n0 + row) * 384 + ks * 32 + kc * 8);
    };
    auto stq = [&](int base, int row, int kc, uint4 v) {
        *(uint4*)(lds + base + row * 80 + kc * 16) = v;
    };

    {
        uint4 a1 = loadA(0, ar1, ak1), a2 = loadA(0, ar2, ak2);
        uint4 w1 = loadW(0, ar1, ak1), w2 = loadW(0, ar2, ak2);
        stq(AB0, ar1, ak1, a1); stq(AB0, ar2, ak2, a2);
        stq(WB0, ar1, ak1, w1); stq(WB0, ar2, ak2, w2);
    }
    __syncthreads();

    for (int ks = 0; ks < 12; ++ks) {
        const int cb = ks & 1;
        uint4 a1, a2, w1, w2;
        if (ks < 11) {
            a1 = loadA(ks + 1, ar1, ak1); a2 = loadA(ks + 1, ar2, ak2);
            w1 = loadW(ks + 1, ar1, ak1); w2 = loadW(ks + 1, ar2, ak2);
        }
        const int ab = cb ? AB1 : AB0;
        const int wb = cb ? WB1 : WB0;
        short8 af[4], bfr[4];
        #pragma unroll
        for (int i = 0; i < 4; ++i) {
            af[i]  = *(const short8*)(lds + ab + (wm * 64 + i * 16 + l15) * 80 + l4 * 16);
            bfr[i] = *(const short8*)(lds + wb + (wn * 64 + i * 16 + l15) * 80 + l4 * 16);
        }
        #pragma unroll
        for (int i = 0; i < 4; ++i)
            #pragma unroll
            for (int j = 0; j < 4; ++j)
                acc[i][j] = __builtin_amdgcn_mfma_f32_16x16x32_bf16(af[i], bfr[j], acc[i][j], 0, 0, 0);
        if (ks < 11) {
            const int nab = cb ? AB0 : AB1;
            const int nwb = cb ? WB0 : WB1;
            stq(nab, ar1, ak1, a1); stq(nab, ar2, ak2, a2);
            stq(nwb, ar1, ak1, w1); stq(nwb, ar2, ak2, w2);
        }
        __syncthreads();
    }

    // epilogue: lanes 4u+{0,1,2,3} hold (r,z,xn,hn) pre-activations, same rows
    #pragma unroll
    for (int mi = 0; mi < 4; ++mi) {
        const int mb = m0 + wm * 64 + mi * 16 + l4 * 4;
        #pragma unroll
        for (int ni = 0; ni < 4; ++ni) {
            const int colg = n0 + wn * 64 + ni * 16 + l15;
            const float bs = biasb[colg];
            #pragma unroll
            for (int j = 0; j < 4; ++j) {
                float s  = acc[mi][ni][j] + bs;
                float s1 = __shfl_xor(s, 1);
                float s2 = __shfl_xor(s, 2);
                float s3 = __shfl_xor(s, 3);
                if ((lane & 3) == 0) {
                    const int m = mb + j;
                    const int u = colg >> 2;
                    float r  = sigmoidf_(s);
                    float z  = sigmoidf_(s1);
                    float ng = tanhf_(s2 + r * s3);
                    float hp = hfp[(size_t)m * 256 + u];
                    float hn = (1.f - z) * ng + z * hp;
                    hfp[(size_t)m * 256 + u] = hn;
                    hnxt[(size_t)m * 256 + u] = f2bf(hn);
                    if (t == len[m] - 1) his_last[(size_t)m * 256 + u] = hn;
                }
            }
        }
    }
}

// ---------------------------------------------------------------------------
// Intra GRU, weight-STREAMING version (no per-thread arrays -> no spill).
// 16 blocks x 256 threads. Thread u owns w_hh rows {u, 256+u, 512+u} (bf16),
// streamed from L2 every step; h broadcast from LDS; gates combined inline.
// ---------------------------------------------------------------------------
__global__ __launch_bounds__(256) void intra_gru_stream(
    const unsigned short* __restrict__ whh,  // (768,256) bf16
    const float* __restrict__ b_hh,
    const float* __restrict__ xw,   // (1024,768): [xr|xz|xn] per (b,t)
    float* __restrict__ ih)         // (1024,256)
{
    __shared__ __align__(16) float hs[H_];
    const int b = blockIdx.x, u = threadIdx.x;
    const uint4* wr_p = (const uint4*)(whh + (size_t)u * 256);
    const uint4* wz_p = (const uint4*)(whh + (size_t)(256 + u) * 256);
    const uint4* wn_p = (const uint4*)(whh + (size_t)(512 + u) * 256);
    const float br = b_hh[u], bz = b_hh[256 + u], bn = b_hh[512 + u];
    hs[u] = 0.f;
    __syncthreads();

    for (int t = 0; t < S_; ++t) {
        const float* xp = xw + ((size_t)b * S_ + t) * 768;
        float xr = xp[u], xz = xp[256 + u], xn = xp[512 + u];
        float ar = br,  az = bz,  an = bn;
        float ar1 = 0.f, az1 = 0.f, an1 = 0.f;
        #pragma unroll 4
        for (int i = 0; i < 32; ++i) {
            uint4 wr4 = wr_p[i];
            uint4 wz4 = wz_p[i];
            uint4 wn4 = wn_p[i];
            float4 h0 = *(const float4*)&hs[i * 8];
            float4 h1 = *(const float4*)&hs[i * 8 + 4];
            BF2(h0.x, h0.y, wr4.x, ar, ar1); BF2(h0.z, h0.w, wr4.y, ar, ar1);
            BF2(h1.x, h1.y, wr4.z, ar, ar1); BF2(h1.z, h1.w, wr4.w, ar, ar1);
            BF2(h0.x, h0.y, wz4.x, az, az1); BF2(h0.z, h0.w, wz4.y, az, az1);
            BF2(h1.x, h1.y, wz4.z, az, az1); BF2(h1.z, h1.w, wz4.w, az, az1);
            BF2(h0.x, h0.y, wn4.x, an, an1); BF2(h0.z, h0.w, wn4.y, an, an1);
            BF2(h1.x, h1.y, wn4.z, an, an1); BF2(h1.z, h1.w, wn4.w, an, an1);
        }
        float r = sigmoidf_(xr + (ar + ar1));
        float z = sigmoidf_(xz + (az + az1));
        float n = tanhf_(xn + r * (an + an1));
        float hnew = (1.f - z) * n + z * hs[u];
        __syncthreads();
        hs[u] = hnew;
        ih[((size_t)b * S_ + t) * H_ + u] = hnew;
        __syncthreads();
    }
}

// ---------------------------------------------------------------------------
// Concat / pack kernels
// ---------------------------------------------------------------------------
__global__ void concat_mrv(const float* __restrict__ hl, const float* __restrict__ ir,
                           float* __restrict__ Mrv)
{
    int idx = blockIdx.x * 256 + threadIdx.x;          // BSR_*384
    if (idx >= BSR_ * 384) return;
    int c = idx % 384, pr = idx / 384;
    Mrv[idx] = (c < 256) ? hl[(size_t)pr * 256 + c] : ir[(size_t)pr * 128 + (c - 256)];
}

__global__ void concat_mpv(const float* __restrict__ ihf, const float* __restrict__ x,
                           float* __restrict__ mpv)
{
    int idx = blockIdx.x * 256 + threadIdx.x;          // BS_*384
    if (idx >= BS_ * 384) return;
    int c = idx % 384, p = idx / 384;
    float v = 0.f;
    if (c < 256)      v = ihf[(size_t)p * 256 + c];
    else if (c < 383) v = x[(size_t)p * 128 + (c - 256)];
    mpv[idx] = v;
}

__global__ void concat_ihp(const float* __restrict__ ihf, const float* __restrict__ x,
                           float* __restrict__ ihp)
{
    int idx = blockIdx.x * 256 + threadIdx.x;          // BS_*260
    if (idx >= BS_ * 260) return;
    int c = idx % 260, p = idx / 260;
    float v = 0.f;
    if (c < 256)       v = ihf[(size_t)p * 256 + c];
    else if (c == 256) v = x[(size_t)p * 128 + 127];
    ihp[idx] = v;
}

__global__ void combine_feat(const float* __restrict__ vv, const float* __restrict__ vh,
                             const float* __restrict__ ihf, const float* __restrict__ x,
                             const float* __restrict__ wr, float* __restrict__ feat)
{
    int idx = blockIdx.x * 256 + threadIdx.x;          // BS_*640
    if (idx >= BS_ * 640) return;
    int c = idx % 640, p = idx / 640;
    float e0 = __expf(wr[0]), e1 = __expf(wr[1]);
    float w0 = e0 / (e0 + e1), w1 = e1 / (e0 + e1);
    float v = 0.f;
    if (c < 256)      v = w0 * vv[(size_t)p * 256 + c] + w1 * vh[(size_t)p * 256 + c];
    else if (c < 512) v = ihf[(size_t)p * 256 + (c - 256)];
    else if (c < 639) v = x[(size_t)p * 128 + (c - 512)];
    feat[idx] = v;
}

// ---------------------------------------------------------------------------
// v_v attention: R=6 keys, 1 query per (p, head). One wave per (p, head).
// ---------------------------------------------------------------------------
__global__ __launch_bounds__(256) void attn_vv(
    const float* __restrict__ q, const float* __restrict__ k,
    const float* __restrict__ v, float* __restrict__ o)
{
    int wid = (blockIdx.x * 256 + threadIdx.x) >> 6;
    int lane = threadIdx.x & 63;
    int p = wid >> 1, head = wid & 1;
    int d0 = head * 128 + lane * 2;
    const float* qp = q + (size_t)p * 256 + d0;
    float q0 = qp[0], q1 = qp[1];
    float sc[R_];
    #pragma unroll
    for (int r = 0; r < R_; ++r) {
        const float* kp = k + (size_t)(p * R_ + r) * 256 + d0;
        float s = q0 * kp[0] + q1 * kp[1];
        #pragma unroll
        for (int off = 32; off; off >>= 1) s += __shfl_xor(s, off, 64);
        sc[r] = s * 0.08838834764831845f;
    }
    float mx = sc[0];
    #pragma unroll
    for (int r = 1; r < R_; ++r) mx = fmaxf(mx, sc[r]);
    float sum = 0.f;
    #pragma unroll
    for (int r = 0; r < R_; ++r) { sc[r] = __expf(sc[r] - mx); sum += sc[r]; }
    float inv = 1.f / sum;
    float o0 = 0.f, o1 = 0.f;
    #pragma unroll
    for (int r = 0; r < R_; ++r) {
        const float* vp = v + (size_t)(p * R_ + r) * 256 + d0;
        o0 += sc[r] * vp[0];
        o1 += sc[r] * vp[1];
    }
    o[(size_t)p * 256 + d0]     = o0 * inv;
    o[(size_t)p * 256 + d0 + 1] = o1 * inv;
}

// ---------------------------------------------------------------------------
// v_h attention: causal 64x64 per (b, head). One wave per (b, head, q-row).
// ---------------------------------------------------------------------------
__global__ __launch_bounds__(256) void attn_vh(
    const float* __restrict__ q, const float* __restrict__ k,
    const float* __restrict__ v, float* __restrict__ o)
{
    __shared__ float ps[4][64];
    int widb = threadIdx.x >> 6;
    int wid = blockIdx.x * 4 + widb;
    int lane = threadIdx.x & 63;
    int b = wid >> 7;
    int rem = wid & 127;
    int head = rem >> 6;
    int qi = rem & 63;
    const float* qrow = q + ((size_t)b * 64 + qi) * 256 + head * 128;
    const float* krow = k + ((size_t)b * 64 + lane) * 256 + head * 128;
    float sA = 0.f, sB = 0.f;
    for (int d = 0; d < 128; d += 2) {
        sA = fmaf(qrow[d],     krow[d],     sA);
        sB = fmaf(qrow[d + 1], krow[d + 1], sB);
    }
    float s = (sA + sB) * 0.08838834764831845f;
    bool valid = (lane <= qi);
    float smax = valid ? s : -1e30f;
    #pragma unroll
    for (int off = 32; off; off >>= 1) smax = fmaxf(smax, __shfl_xor(smax, off, 64));
    float e = valid ? __expf(s - smax) : 0.f;
    float ssum = e;
    #pragma unroll
    for (int off = 32; off; off >>= 1) ssum += __shfl_xor(ssum, off, 64);
    float pv = e / ssum;
    ps[widb][lane] = pv;
    __syncthreads();
    float o0 = 0.f, o1 = 0.f;
    for (int j = 0; j <= qi; ++j) {
        float pj = ps[widb][j];
        const float* vrow = v + ((size_t)b * 64 + j) * 256 + head * 128;
        o0 = fmaf(pj, vrow[lane],      o0);
        o1 = fmaf(pj, vrow[lane + 64], o1);
    }
    o[((size_t)b * 64 + qi) * 256 + head * 128 + lane]      = o0;
    o[((size_t)b * 64 + qi) * 256 + head * 128 + lane + 64] = o1;
}

// ---------------------------------------------------------------------------
extern "C" void kernel_launch(void* const* d_in, const int* in_sizes, int n_in,
                              void* d_out, int out_size, void* d_ws, size_t ws_size,
                              hipStream_t stream)
{
    const float* intra_x   = (const float*)d_in[0];
    const float* inter_his = (const float*)d_in[1];
    const float* inter_r   = (const float*)d_in[2];
    const int*   inter_len = (const int*)  d_in[4];
    const float* w_ih = (const float*)d_in[5];
    const float* w_hh = (const float*)d_in[6];
    const float* b_ih = (const float*)d_in[7];
    const float* b_hh = (const float*)d_in[8];
    const float* iq_w = (const float*)d_in[9];
    const float* iq_b = (const float*)d_in[10];
    const float* ik_w = (const float*)d_in[11];
    const float* ik_b = (const float*)d_in[12];
    const float* iv_w = (const float*)d_in[13];
    const float* iv_b = (const float*)d_in[14];
    const float* io_w = (const float*)d_in[15];
    const float* io_b = (const float*)d_in[16];
    const float* aq_w = (const float*)d_in[17];
    const float* aq_b = (const float*)d_in[18];
    const float* ak_w = (const float*)d_in[19];
    const float* ak_b = (const float*)d_in[20];
    const float* av_w = (const float*)d_in[21];
    const float* av_b = (const float*)d_in[22];
    const float* ao_w = (const float*)d_in[23];
    const float* ao_b = (const float*)d_in[24];
    const float* wr   = (const float*)d_in[25];
    const float* ln_w = (const float*)d_in[26];
    const float* ln_b = (const float*)d_in[27];
    float* out = (float*)d_out;

    char* ws = (char*)d_ws;
    size_t off = 0;
    auto alloc = [&](size_t bytes) -> void* {
        char* p = ws + off;
        off += (bytes + 255) & ~(size_t)255;
        return (void*)p;
    };
    unsigned short* Wbg  = (unsigned short*)alloc((size_t)1024 * 384 * 2);
    unsigned short* whhb = (unsigned short*)alloc((size_t)768 * 256 * 2);
    float* biasb   = (float*)alloc(1024 * 4);
    unsigned short* hbf0 = (unsigned short*)alloc((size_t)BSR_ * H_ * 2);
    unsigned short* hbf1 = (unsigned short*)alloc((size_t)BSR_ * H_ * 2);
    float* hfp     = (float*)alloc((size_t)BSR_ * H_ * 4);
    float* hislast = (float*)alloc((size_t)BSR_ * H_ * 4);
    float* intraH  = (float*)alloc((size_t)BS_ * H_ * 4);
    float* xwI     = (float*)alloc((size_t)BS_ * 768 * 4);
    float* Mrv     = (float*)alloc((size_t)BSR_ * 384 * 4);
    float* mpv     = (float*)alloc((size_t)BS_ * 384 * 4);
    float* qbuf    = (float*)alloc((size_t)BS_ * 256 * 4);
    float* kbuf    = (float*)alloc((size_t)BSR_ * 256 * 4);
    float* vbuf    = (float*)alloc((size_t)BSR_ * 256 * 4);
    float* attno   = (float*)alloc((size_t)BS_ * 256 * 4);
    float* vv      = (float*)alloc((size_t)BS_ * 256 * 4);
    float* ihp     = (float*)alloc((size_t)BS_ * 260 * 4);
    float* qa      = (float*)alloc((size_t)BS_ * 256 * 4);
    float* ka      = (float*)alloc((size_t)BS_ * 256 * 4);
    float* va      = (float*)alloc((size_t)BS_ * 256 * 4);
    float* aho     = (float*)alloc((size_t)BS_ * 256 * 4);
    float* vhb     = (float*)alloc((size_t)BS_ * 256 * 4);
    float* feat    = (float*)alloc((size_t)BS_ * 640 * 4);
    (void)ws_size; (void)in_sizes; (void)n_in; (void)out_size;

    auto gemm = [&](const float* A, int lda, const float* Bw, int ldb,
                    const float* bias, float* C, int M, int N, int K) {
        gemm_k<<<dim3((M + BM - 1) / BM, (N + BN - 1) / BN), 256, 0, stream>>>(
            A, lda, K, A, 0, Bw, ldb, bias, C, N, M, N, K);
    };

    // weight prep + state init
    prep_wbig<<<1536, 256, 0, stream>>>(w_ih, w_hh, b_ih, b_hh, Wbg, biasb);
    prep_whh<<<768, 256, 0, stream>>>(w_hh, whhb);
    hipMemsetAsync(hbf0, 0, (size_t)BSR_ * H_ * 2, stream);
    hipMemsetAsync(hfp,  0, (size_t)BSR_ * H_ * 4, stream);

    // intra GRU: x-projection GEMM + weight-streaming recurrence
    gemm(intra_x, 128, w_ih, 128, b_ih, xwI, BS_, 768, 128);
    intra_gru_stream<<<B_, 256, 0, stream>>>(whhb, b_hh, xwI, intraH);

    // inter GRU: 24 MFMA steps with fused gate epilogue
    for (int t = 0; t < L_; ++t) {
        const unsigned short* hc = (t & 1) ? hbf1 : hbf0;
        unsigned short* hx       = (t & 1) ? hbf0 : hbf1;
        gru_step<<<dim3(BSR_ / 128, 1024 / 128), 256, 0, stream>>>(
            inter_his, Wbg, biasb, hc, hx, hfp, hislast, inter_len, t);
    }

    // v_v branch
    concat_mrv<<<(BSR_ * 384 + 255) / 256, 256, 0, stream>>>(hislast, inter_r, Mrv);
    concat_mpv<<<(BS_ * 384 + 255) / 256, 256, 0, stream>>>(intraH, intra_x, mpv);
    gemm(mpv, 384, iq_w, 383, iq_b, qbuf, BS_, 256, 383);
    gemm(Mrv, 384, ik_w, 383, ik_b, kbuf, BSR_, 256, 383);
    gemm(Mrv, 384, iv_w, 384, iv_b, vbuf, BSR_, 256, 384);
    attn_vv<<<512, 256, 0, stream>>>(qbuf, kbuf, vbuf, attno);
    gemm(attno, 256, io_w, 256, io_b, vv, BS_, 256, 256);

    // v_h branch
    concat_ihp<<<(BS_ * 260 + 255) / 256, 256, 0, stream>>>(intraH, intra_x, ihp);
    gemm(intra_x, 128, aq_w, 127, aq_b, qa, BS_, 256, 127);
    gemm(intra_x, 128, ak_w, 127, ak_b, ka, BS_, 256, 127);
    gemm(ihp, 260, av_w, 257, av_b, va, BS_, 256, 257);
    attn_vh<<<512, 256, 0, stream>>>(qa, ka, va, aho);
    gemm(aho, 256, ao_w, 256, ao_b, vhb, BS_, 256, 256);

    // combine + final projection
    combine_feat<<<(BS_ * 640 + 255) / 256, 256, 0, stream>>>(vv, vhb, intraH, intra_x, wr, feat);
    gemm(feat, 640, ln_w, 639, ln_b, out, BS_, 256, 639);
}

// Round 7
// 1515.778 us; speedup vs baseline: 4.1795x; 1.4926x over previous
//
#include <hip/hip_runtime.h>
#include <hip/hip_bf16.h>
#include <math.h>

// Shapes
#define B_  16
#define S_  64
#define R_  6
#define L_  24
#define D_  128
#define H_  256
#define BS_   1024    // B*S
#define BSR_  6144    // B*S*R

typedef __attribute__((ext_vector_type(8))) short short8;
typedef __attribute__((ext_vector_type(4))) float f32x4;

__device__ __forceinline__ float sigmoidf_(float x) { return 1.f / (1.f + __expf(-x)); }
// fast tanh via __expf (no ocml libcall)
__device__ __forceinline__ float tanhf_(float x) {
    float e = __expf(2.f * x);
    return 1.f - 2.f / (e + 1.f);
}

// RNE float->bf16 helpers
__device__ __forceinline__ unsigned short f2bf(float f) {
    unsigned int u = __float_as_uint(f);
    u = (u + 0x7fff + ((u >> 16) & 1)) >> 16;
    return (unsigned short)u;
}
__device__ __forceinline__ unsigned int pack2(float a, float b) {
    unsigned int ua = __float_as_uint(a), ub = __float_as_uint(b);
    ua = (ua + 0x7fff + ((ua >> 16) & 1)) >> 16;
    ub = (ub + 0x7fff + ((ub >> 16) & 1)) & 0xffff0000u;
    return (ua & 0xffffu) | ub;
}

// ---------------------------------------------------------------------------
// fp32 tiled GEMM (small projections): C[m,n] = bias[n] + sum_k A(m,k)*B[n*ldb+k]
// A(m,k) = (k < K1) ? A1[m*lda1+k] : A2[m*lda2+(k-K1)]
// ---------------------------------------------------------------------------
#define BM 64
#define BN 64
#define BK 16

__global__ __launch_bounds__(256) void gemm_k(
    const float* __restrict__ A1, int lda1, int K1,
    const float* __restrict__ A2, int lda2,
    const float* __restrict__ Bm, int ldb,
    const float* __restrict__ bias,
    float* __restrict__ C, int ldc,
    int M, int N, int K)
{
    __shared__ float As[BK][BM + 4];
    __shared__ float Bs[BK][BN + 4];
    const int tid = threadIdx.x;
    const int m0 = blockIdx.x * BM;
    const int n0 = blockIdx.y * BN;
    const int tx = tid & 15, ty = tid >> 4;
    const int lr  = tid >> 2;
    const int lk0 = (tid & 3) << 2;
    float acc[4][4] = {};

    for (int k0 = 0; k0 < K; k0 += BK) {
        #pragma unroll
        for (int i = 0; i < 4; ++i) {
            int k = k0 + lk0 + i;
            int m = m0 + lr;
            float va = 0.f;
            if (m < M && k < K)
                va = (k < K1) ? A1[(size_t)m * lda1 + k]
                              : A2[(size_t)m * lda2 + (k - K1)];
            As[lk0 + i][lr] = va;
            int nn = n0 + lr;
            float vb = 0.f;
            if (nn < N && k < K) vb = Bm[(size_t)nn * ldb + k];
            Bs[lk0 + i][lr] = vb;
        }
        __syncthreads();
        #pragma unroll
        for (int kk = 0; kk < BK; ++kk) {
            const float4 a4 = *(const float4*)&As[kk][ty << 2];
            const float4 b4 = *(const float4*)&Bs[kk][tx << 2];
            const float a[4] = {a4.x, a4.y, a4.z, a4.w};
            const float b[4] = {b4.x, b4.y, b4.z, b4.w};
            #pragma unroll
            for (int i = 0; i < 4; ++i)
                #pragma unroll
                for (int j = 0; j < 4; ++j)
                    acc[i][j] = fmaf(a[i], b[j], acc[i][j]);
        }
        __syncthreads();
    }
    #pragma unroll
    for (int i = 0; i < 4; ++i) {
        int m = m0 + (ty << 2) + i;
        if (m >= M) continue;
        #pragma unroll
        for (int j = 0; j < 4; ++j) {
            int nn = n0 + (tx << 2) + j;
            if (nn < N) C[(size_t)m * ldc + nn] = acc[i][j] + bias[nn];
        }
    }
}

// ---------------------------------------------------------------------------
// Wbig bf16 (1024 x 384) + biasb fp32 (1024), interleaved gate quadruples
// ---------------------------------------------------------------------------
__global__ void prep_wbig(const float* __restrict__ w_ih, const float* __restrict__ w_hh,
                          const float* __restrict__ b_ih, const float* __restrict__ b_hh,
                          unsigned short* __restrict__ Wbg, float* __restrict__ biasb)
{
    int idx = blockIdx.x * 256 + threadIdx.x;
    if (idx >= 1024 * 384) return;
    int row = idx / 384, k = idx % 384;
    int j = row >> 2, c = row & 3;
    float v = 0.f;
    if (c == 0)      v = (k < 128) ? w_ih[j * 128 + k]          : w_hh[j * 256 + (k - 128)];
    else if (c == 1) v = (k < 128) ? w_ih[(256 + j) * 128 + k]  : w_hh[(256 + j) * 256 + (k - 128)];
    else if (c == 2) v = (k < 128) ? w_ih[(512 + j) * 128 + k]  : 0.f;
    else             v = (k < 128) ? 0.f                         : w_hh[(512 + j) * 256 + (k - 128)];
    Wbg[idx] = f2bf(v);
    if (k == 0) {
        float bb;
        if (c == 0)      bb = b_ih[j] + b_hh[j];
        else if (c == 1) bb = b_ih[256 + j] + b_hh[256 + j];
        else if (c == 2) bb = b_ih[512 + j];
        else             bb = b_hh[512 + j];
        biasb[row] = bb;
    }
}

// w_hh -> bf16, natural row order (768 x 256)
__global__ void prep_whh(const float* __restrict__ w, unsigned short* __restrict__ wb)
{
    int idx = blockIdx.x * 256 + threadIdx.x;
    if (idx < 768 * 256) wb[idx] = f2bf(w[idx]);
}

// ---------------------------------------------------------------------------
// Inter-GRU step: C(6144x1024) = [x_t | h_t](bf16) @ Wbig^T + fused gate epilogue.
// MFMA 16x16x32; tile 64x128 (M x N), 4 waves (1x4), BK=32, dbuf LDS, 80B rows.
// Grid 96x8 = 768 blocks -> 3 blocks/CU.
// ---------------------------------------------------------------------------
__global__ __launch_bounds__(256) void gru_step(
    const float* __restrict__ his,            // (6144,24,128) fp32
    const unsigned short* __restrict__ Wbg,   // (1024,384) bf16
    const float* __restrict__ biasb,          // (1024)
    const unsigned short* __restrict__ hcur,  // (6144,256) bf16
    unsigned short* __restrict__ hnxt,        // (6144,256) bf16
    float* __restrict__ hfp,                  // (6144,256) fp32, in-place state
    float* __restrict__ his_last,             // (6144,256) fp32
    const int* __restrict__ len, int t)
{
    __shared__ __align__(16) char lds[30720];
    const int tid = threadIdx.x;
    const int lane = tid & 63, wn = tid >> 6;       // wave owns 32 N-cols
    const int l15 = lane & 15, l4 = lane >> 4;
    const int m0 = blockIdx.x * 64, n0 = blockIdx.y * 128;

    const int r_ = tid >> 2, c_ = tid & 3;          // staging row/kslot

    const int A0 = 0, A1 = 5120, W0 = 10240, W1 = 20480;

    f32x4 acc[4][2] = {};

    auto loadA = [&](int ks, int row, int kc) -> uint4 {
        if (ks < 4) {
            const float* p = his + ((size_t)(m0 + row) * 24 + t) * 128 + ks * 32 + kc * 8;
            float4 f0 = *(const float4*)p;
            float4 f1 = *(const float4*)(p + 4);
            uint4 r;
            r.x = pack2(f0.x, f0.y); r.y = pack2(f0.z, f0.w);
            r.z = pack2(f1.x, f1.y); r.w = pack2(f1.z, f1.w);
            return r;
        }
        return *(const uint4*)(hcur + (size_t)(m0 + row) * 256 + (ks - 4) * 32 + kc * 8);
    };
    auto loadW = [&](int ks, int row, int kc) -> uint4 {
        return *(const uint4*)(Wbg + (size_t)(n0 + row) * 384 + ks * 32 + kc * 8);
    };
    auto stq = [&](int base, int row, int kc, uint4 v) {
        *(uint4*)(lds + base + row * 80 + kc * 16) = v;
    };

    {
        uint4 a1 = loadA(0, r_, c_);
        uint4 w1 = loadW(0, r_, c_), w2 = loadW(0, r_ + 64, c_);
        stq(A0, r_, c_, a1); stq(W0, r_, c_, w1); stq(W0, r_ + 64, c_, w2);
    }
    __syncthreads();

    for (int ks = 0; ks < 12; ++ks) {
        const int cb = ks & 1;
        uint4 a1, w1, w2;
        if (ks < 11) {
            a1 = loadA(ks + 1, r_, c_);
            w1 = loadW(ks + 1, r_, c_); w2 = loadW(ks + 1, r_ + 64, c_);
        }
        const int ab = cb ? A1 : A0;
        const int wb = cb ? W1 : W0;
        short8 af[4], bfr[2];
        #pragma unroll
        for (int i = 0; i < 4; ++i)
            af[i]  = *(const short8*)(lds + ab + (i * 16 + l15) * 80 + l4 * 16);
        #pragma unroll
        for (int j = 0; j < 2; ++j)
            bfr[j] = *(const short8*)(lds + wb + (wn * 32 + j * 16 + l15) * 80 + l4 * 16);
        #pragma unroll
        for (int i = 0; i < 4; ++i)
            #pragma unroll
            for (int j = 0; j < 2; ++j)
                acc[i][j] = __builtin_amdgcn_mfma_f32_16x16x32_bf16(af[i], bfr[j], acc[i][j], 0, 0, 0);
        if (ks < 11) {
            const int nab = cb ? A0 : A1;
            const int nwb = cb ? W0 : W1;
            stq(nab, r_, c_, a1); stq(nwb, r_, c_, w1); stq(nwb, r_ + 64, c_, w2);
        }
        __syncthreads();
    }

    // epilogue: lanes 4u+{0,1,2,3} hold (r,z,xn,hn) pre-activations, same rows
    #pragma unroll
    for (int mi = 0; mi < 4; ++mi) {
        const int mb = m0 + mi * 16 + l4 * 4;
        #pragma unroll
        for (int ni = 0; ni < 2; ++ni) {
            const int colg = n0 + wn * 32 + ni * 16 + l15;
            const float bs = biasb[colg];
            #pragma unroll
            for (int j = 0; j < 4; ++j) {
                float s  = acc[mi][ni][j] + bs;
                float s1 = __shfl_xor(s, 1);
                float s2 = __shfl_xor(s, 2);
                float s3 = __shfl_xor(s, 3);
                if ((lane & 3) == 0) {
                    const int m = mb + j;
                    const int u = colg >> 2;
                    float r  = sigmoidf_(s);
                    float z  = sigmoidf_(s1);
                    float ng = tanhf_(s2 + r * s3);
                    float hp = hfp[(size_t)m * 256 + u];
                    float hn = (1.f - z) * ng + z * hp;
                    hfp[(size_t)m * 256 + u] = hn;
                    hnxt[(size_t)m * 256 + u] = f2bf(hn);
                    if (t == len[m] - 1) his_last[(size_t)m * 256 + u] = hn;
                }
            }
        }
    }
}

// ---------------------------------------------------------------------------
// Intra GRU, persistent single-block MFMA kernel.
// 512 threads (8 waves). Per step: G(16x768) = H(16x256) @ Whh^T via MFMA,
// wave w owns cols [96w, 96w+96) with B-fragments in 192 VGPRs (held across
// all 64 steps). Gate phase: 512 threads, xw prefetched to regs pre-barrier.
// Fragment layouts identical to the bench-verified gru_step mappings.
// ---------------------------------------------------------------------------
__global__ __launch_bounds__(512, 2) void intra_gru_mfma(
    const unsigned short* __restrict__ whhb,  // (768,256) bf16, rows [r|z|n]
    const float* __restrict__ b_hh,           // (768)
    const float* __restrict__ xw,             // (1024,768) fp32 [xr|xz|xn]
    float* __restrict__ ih)                   // (1024,256) fp32
{
    __shared__ __align__(16) unsigned short hs_bf[16 * 264];  // bf16 A-operand, padded rows
    __shared__ float hf[16 * 256];                            // fp32 h state
    __shared__ float G[16 * 768];                             // gate pre-activations
    const int tid = threadIdx.x;
    const int lane = tid & 63, wv = tid >> 6;
    const int l15 = lane & 15, l4 = lane >> 4;
    const int cw = wv * 96;

    // one-time: weight fragments -> registers (static-indexed, fully unrolled)
    short8 wfr[6][8];
    #pragma unroll
    for (int ni = 0; ni < 6; ++ni)
        #pragma unroll
        for (int kk = 0; kk < 8; ++kk)
            wfr[ni][kk] = *(const short8*)(whhb + (size_t)(cw + ni * 16 + l15) * 256 + kk * 32 + l4 * 8);

    const int u = tid & 255, q = tid >> 8;
    const float br = b_hh[u], bz = b_hh[256 + u], bn = b_hh[512 + u];

    #pragma unroll
    for (int p = 0; p < 8; ++p) hf[tid + p * 512] = 0.f;
    #pragma unroll
    for (int p = 0; p < 9; ++p) { int i = tid + p * 512; if (i < 16 * 264) hs_bf[i] = 0; }
    __syncthreads();

    for (int t = 0; t < S_; ++t) {
        // MFMA phase: A = h (16 x 256), row = batch = l15, k-slice = kk*32+l4*8
        f32x4 acc[6] = {};
        #pragma unroll
        for (int kk = 0; kk < 8; ++kk) {
            short8 a = *(const short8*)&hs_bf[l15 * 264 + kk * 32 + l4 * 8];
            #pragma unroll
            for (int ni = 0; ni < 6; ++ni)
                acc[ni] = __builtin_amdgcn_mfma_f32_16x16x32_bf16(a, wfr[ni][kk], acc[ni], 0, 0, 0);
        }
        // C/D: col = l15 (gate idx), row = l4*4+j (batch) -> G[batch][gate]
        #pragma unroll
        for (int ni = 0; ni < 6; ++ni)
            #pragma unroll
            for (int j = 0; j < 4; ++j)
                G[(l4 * 4 + j) * 768 + cw + ni * 16 + l15] = acc[ni][j];

        // prefetch xw for this step; barrier drain hides the latency
        float xr8[8], xz8[8], xn8[8];
        #pragma unroll
        for (int p = 0; p < 8; ++p) {
            const float* xp = xw + ((size_t)((q + 2 * p) << 6) + t) * 768 + u;
            xr8[p] = xp[0]; xz8[p] = xp[256]; xn8[p] = xp[512];
        }
        __syncthreads();

        // gate phase: thread handles unit u for batches q, q+2, ..., q+14
        #pragma unroll
        for (int p = 0; p < 8; ++p) {
            const int m = q + 2 * p;
            float r = sigmoidf_(xr8[p] + G[m * 768 + u]       + br);
            float z = sigmoidf_(xz8[p] + G[m * 768 + 256 + u] + bz);
            float n = tanhf_(xn8[p] + r * (G[m * 768 + 512 + u] + bn));
            float hold = hf[m * 256 + u];
            float hnew = (1.f - z) * n + z * hold;
            hf[m * 256 + u] = hnew;
            hs_bf[m * 264 + u] = f2bf(hnew);
            ih[(size_t)((m << 6) + t) * 256 + u] = hnew;
        }
        __syncthreads();
    }
}

// ---------------------------------------------------------------------------
// Concat / pack kernels
// ---------------------------------------------------------------------------
__global__ void concat_mrv(const float* __restrict__ hl, const float* __restrict__ ir,
                           float* __restrict__ Mrv)
{
    int idx = blockIdx.x * 256 + threadIdx.x;          // BSR_*384
    if (idx >= BSR_ * 384) return;
    int c = idx % 384, pr = idx / 384;
    Mrv[idx] = (c < 256) ? hl[(size_t)pr * 256 + c] : ir[(size_t)pr * 128 + (c - 256)];
}

__global__ void concat_mpv(const float* __restrict__ ihf, const float* __restrict__ x,
                           float* __restrict__ mpv)
{
    int idx = blockIdx.x * 256 + threadIdx.x;          // BS_*384
    if (idx >= BS_ * 384) return;
    int c = idx % 384, p = idx / 384;
    float v = 0.f;
    if (c < 256)      v = ihf[(size_t)p * 256 + c];
    else if (c < 383) v = x[(size_t)p * 128 + (c - 256)];
    mpv[idx] = v;
}

__global__ void concat_ihp(const float* __restrict__ ihf, const float* __restrict__ x,
                           float* __restrict__ ihp)
{
    int idx = blockIdx.x * 256 + threadIdx.x;          // BS_*260
    if (idx >= BS_ * 260) return;
    int c = idx % 260, p = idx / 260;
    float v = 0.f;
    if (c < 256)       v = ihf[(size_t)p * 256 + c];
    else if (c == 256) v = x[(size_t)p * 128 + 127];
    ihp[idx] = v;
}

__global__ void combine_feat(const float* __restrict__ vv, const float* __restrict__ vh,
                             const float* __restrict__ ihf, const float* __restrict__ x,
                             const float* __restrict__ wr, float* __restrict__ feat)
{
    int idx = blockIdx.x * 256 + threadIdx.x;          // BS_*640
    if (idx >= BS_ * 640) return;
    int c = idx % 640, p = idx / 640;
    float e0 = __expf(wr[0]), e1 = __expf(wr[1]);
    float w0 = e0 / (e0 + e1), w1 = e1 / (e0 + e1);
    float v = 0.f;
    if (c < 256)      v = w0 * vv[(size_t)p * 256 + c] + w1 * vh[(size_t)p * 256 + c];
    else if (c < 512) v = ihf[(size_t)p * 256 + (c - 256)];
    else if (c < 639) v = x[(size_t)p * 128 + (c - 512)];
    feat[idx] = v;
}

// ---------------------------------------------------------------------------
// v_v attention: R=6 keys, 1 query per (p, head). One wave per (p, head).
// ---------------------------------------------------------------------------
__global__ __launch_bounds__(256) void attn_vv(
    const float* __restrict__ q, const float* __restrict__ k,
    const float* __restrict__ v, float* __restrict__ o)
{
    int wid = (blockIdx.x * 256 + threadIdx.x) >> 6;
    int lane = threadIdx.x & 63;
    int p = wid >> 1, head = wid & 1;
    int d0 = head * 128 + lane * 2;
    const float* qp = q + (size_t)p * 256 + d0;
    float q0 = qp[0], q1 = qp[1];
    float sc[R_];
    #pragma unroll
    for (int r = 0; r < R_; ++r) {
        const float* kp = k + (size_t)(p * R_ + r) * 256 + d0;
        float s = q0 * kp[0] + q1 * kp[1];
        #pragma unroll
        for (int off = 32; off; off >>= 1) s += __shfl_xor(s, off, 64);
        sc[r] = s * 0.08838834764831845f;
    }
    float mx = sc[0];
    #pragma unroll
    for (int r = 1; r < R_; ++r) mx = fmaxf(mx, sc[r]);
    float sum = 0.f;
    #pragma unroll
    for (int r = 0; r < R_; ++r) { sc[r] = __expf(sc[r] - mx); sum += sc[r]; }
    float inv = 1.f / sum;
    float o0 = 0.f, o1 = 0.f;
    #pragma unroll
    for (int r = 0; r < R_; ++r) {
        const float* vp = v + (size_t)(p * R_ + r) * 256 + d0;
        o0 += sc[r] * vp[0];
        o1 += sc[r] * vp[1];
    }
    o[(size_t)p * 256 + d0]     = o0 * inv;
    o[(size_t)p * 256 + d0 + 1] = o1 * inv;
}

// ---------------------------------------------------------------------------
// v_h attention: causal 64x64 per (b, head). One wave per (b, head, q-row).
// ---------------------------------------------------------------------------
__global__ __launch_bounds__(256) void attn_vh(
    const float* __restrict__ q, const float* __restrict__ k,
    const float* __restrict__ v, float* __restrict__ o)
{
    __shared__ float ps[4][64];
    int widb = threadIdx.x >> 6;
    int wid = blockIdx.x * 4 + widb;
    int lane = threadIdx.x & 63;
    int b = wid >> 7;
    int rem = wid & 127;
    int head = rem >> 6;
    int qi = rem & 63;
    const float* qrow = q + ((size_t)b * 64 + qi) * 256 + head * 128;
    const float* krow = k + ((size_t)b * 64 + lane) * 256 + head * 128;
    float sA = 0.f, sB = 0.f;
    for (int d = 0; d < 128; d += 2) {
        sA = fmaf(qrow[d],     krow[d],     sA);
        sB = fmaf(qrow[d + 1], krow[d + 1], sB);
    }
    float s = (sA + sB) * 0.08838834764831845f;
    bool valid = (lane <= qi);
    float smax = valid ? s : -1e30f;
    #pragma unroll
    for (int off = 32; off; off >>= 1) smax = fmaxf(smax, __shfl_xor(smax, off, 64));
    float e = valid ? __expf(s - smax) : 0.f;
    float ssum = e;
    #pragma unroll
    for (int off = 32; off; off >>= 1) ssum += __shfl_xor(ssum, off, 64);
    float pv = e / ssum;
    ps[widb][lane] = pv;
    __syncthreads();
    float o0 = 0.f, o1 = 0.f;
    for (int j = 0; j <= qi; ++j) {
        float pj = ps[widb][j];
        const float* vrow = v + ((size_t)b * 64 + j) * 256 + head * 128;
        o0 = fmaf(pj, vrow[lane],      o0);
        o1 = fmaf(pj, vrow[lane + 64], o1);
    }
    o[((size_t)b * 64 + qi) * 256 + head * 128 + lane]      = o0;
    o[((size_t)b * 64 + qi) * 256 + head * 128 + lane + 64] = o1;
}

// ---------------------------------------------------------------------------
extern "C" void kernel_launch(void* const* d_in, const int* in_sizes, int n_in,
                              void* d_out, int out_size, void* d_ws, size_t ws_size,
                              hipStream_t stream)
{
    const float* intra_x   = (const float*)d_in[0];
    const float* inter_his = (const float*)d_in[1];
    const float* inter_r   = (const float*)d_in[2];
    const int*   inter_len = (const int*)  d_in[4];
    const float* w_ih = (const float*)d_in[5];
    const float* w_hh = (const float*)d_in[6];
    const float* b_ih = (const float*)d_in[7];
    const float* b_hh = (const float*)d_in[8];
    const float* iq_w = (const float*)d_in[9];
    const float* iq_b = (const float*)d_in[10];
    const float* ik_w = (const float*)d_in[11];
    const float* ik_b = (const float*)d_in[12];
    const float* iv_w = (const float*)d_in[13];
    const float* iv_b = (const float*)d_in[14];
    const float* io_w = (const float*)d_in[15];
    const float* io_b = (const float*)d_in[16];
    const float* aq_w = (const float*)d_in[17];
    const float* aq_b = (const float*)d_in[18];
    const float* ak_w = (const float*)d_in[19];
    const float* ak_b = (const float*)d_in[20];
    const float* av_w = (const float*)d_in[21];
    const float* av_b = (const float*)d_in[22];
    const float* ao_w = (const float*)d_in[23];
    const float* ao_b = (const float*)d_in[24];
    const float* wr   = (const float*)d_in[25];
    const float* ln_w = (const float*)d_in[26];
    const float* ln_b = (const float*)d_in[27];
    float* out = (float*)d_out;

    char* ws = (char*)d_ws;
    size_t off = 0;
    auto alloc = [&](size_t bytes) -> void* {
        char* p = ws + off;
        off += (bytes + 255) & ~(size_t)255;
        return (void*)p;
    };
    unsigned short* Wbg  = (unsigned short*)alloc((size_t)1024 * 384 * 2);
    unsigned short* whhb = (unsigned short*)alloc((size_t)768 * 256 * 2);
    float* biasb   = (float*)alloc(1024 * 4);
    unsigned short* hbf0 = (unsigned short*)alloc((size_t)BSR_ * H_ * 2);
    unsigned short* hbf1 = (unsigned short*)alloc((size_t)BSR_ * H_ * 2);
    float* hfp     = (float*)alloc((size_t)BSR_ * H_ * 4);
    float* hislast = (float*)alloc((size_t)BSR_ * H_ * 4);
    float* intraH  = (float*)alloc((size_t)BS_ * H_ * 4);
    float* xwI     = (float*)alloc((size_t)BS_ * 768 * 4);
    float* Mrv     = (float*)alloc((size_t)BSR_ * 384 * 4);
    float* mpv     = (float*)alloc((size_t)BS_ * 384 * 4);
    float* qbuf    = (float*)alloc((size_t)BS_ * 256 * 4);
    float* kbuf    = (float*)alloc((size_t)BSR_ * 256 * 4);
    float* vbuf    = (float*)alloc((size_t)BSR_ * 256 * 4);
    float* attno   = (float*)alloc((size_t)BS_ * 256 * 4);
    float* vv      = (float*)alloc((size_t)BS_ * 256 * 4);
    float* ihp     = (float*)alloc((size_t)BS_ * 260 * 4);
    float* qa      = (float*)alloc((size_t)BS_ * 256 * 4);
    float* ka      = (float*)alloc((size_t)BS_ * 256 * 4);
    float* va      = (float*)alloc((size_t)BS_ * 256 * 4);
    float* aho     = (float*)alloc((size_t)BS_ * 256 * 4);
    float* vhb     = (float*)alloc((size_t)BS_ * 256 * 4);
    float* feat    = (float*)alloc((size_t)BS_ * 640 * 4);
    (void)ws_size; (void)in_sizes; (void)n_in; (void)out_size;

    auto gemm = [&](const float* A, int lda, const float* Bw, int ldb,
                    const float* bias, float* C, int M, int N, int K) {
        gemm_k<<<dim3((M + BM - 1) / BM, (N + BN - 1) / BN), 256, 0, stream>>>(
            A, lda, K, A, 0, Bw, ldb, bias, C, N, M, N, K);
    };

    // weight prep + state init
    prep_wbig<<<1536, 256, 0, stream>>>(w_ih, w_hh, b_ih, b_hh, Wbg, biasb);
    prep_whh<<<768, 256, 0, stream>>>(w_hh, whhb);
    hipMemsetAsync(hbf0, 0, (size_t)BSR_ * H_ * 2, stream);
    hipMemsetAsync(hfp,  0, (size_t)BSR_ * H_ * 4, stream);

    // intra GRU: x-projection GEMM + persistent MFMA recurrence
    gemm(intra_x, 128, w_ih, 128, b_ih, xwI, BS_, 768, 128);
    intra_gru_mfma<<<1, 512, 0, stream>>>(whhb, b_hh, xwI, intraH);

    // inter GRU: 24 MFMA steps with fused gate epilogue
    for (int t = 0; t < L_; ++t) {
        const unsigned short* hc = (t & 1) ? hbf1 : hbf0;
        unsigned short* hx       = (t & 1) ? hbf0 : hbf1;
        gru_step<<<dim3(BSR_ / 64, 1024 / 128), 256, 0, stream>>>(
            inter_his, Wbg, biasb, hc, hx, hfp, hislast, inter_len, t);
    }

    // v_v branch
    concat_mrv<<<(BSR_ * 384 + 255) / 256, 256, 0, stream>>>(hislast, inter_r, Mrv);
    concat_mpv<<<(BS_ * 384 + 255) / 256, 256, 0, stream>>>(intraH, intra_x, mpv);
    gemm(mpv, 384, iq_w, 383, iq_b, qbuf, BS_, 256, 383);
    gemm(Mrv, 384, ik_w, 383, ik_b, kbuf, BSR_, 256, 383);
    gemm(Mrv, 384, iv_w, 384, iv_b, vbuf, BSR_, 256, 384);
    attn_vv<<<512, 256, 0, stream>>>(qbuf, kbuf, vbuf, attno);
    gemm(attno, 256, io_w, 256, io_b, vv, BS_, 256, 256);

    // v_h branch
    concat_ihp<<<(BS_ * 260 + 255) / 256, 256, 0, stream>>>(intraH, intra_x, ihp);
    gemm(intra_x, 128, aq_w, 127, aq_b, qa, BS_, 256, 127);
    gemm(intra_x, 128, ak_w, 127, ak_b, ka, BS_, 256, 127);
    gemm(ihp, 260, av_w, 257, av_b, va, BS_, 256, 257);
    attn_vh<<<512, 256, 0, stream>>>(qa, ka, va, aho);
    gemm(aho, 256, ao_w, 256, ao_b, vhb, BS_, 256, 256);

    // combine + final projection
    combine_feat<<<(BS_ * 640 + 255) / 256, 256, 0, stream>>>(vv, vhb, intraH, intra_x, wr, feat);
    gemm(feat, 640, ln_w, 639, ln_b, out, BS_, 256, 639);
}